// Round 1
// baseline (2261.748 us; speedup 1.0000x reference)
//
#include <hip/hip_runtime.h>
#include <math.h>

#define NP 8192
#define KN 32

__device__ __forceinline__ float sgnf(float x){ return (x>0.f)?1.f:((x<0.f)?-1.f:0.f); }

// ---------------- prep: pos2, vel2, feats4 ----------------
__global__ __launch_bounds__(256) void k_prep(const float* __restrict__ pos, const float* __restrict__ vel,
                                              float* __restrict__ pos2, float* __restrict__ feats4){
  int i = blockIdx.x*256 + threadIdx.x;
  const float DT = 0.02f;
  float vx = vel[i*3+0], vy = vel[i*3+1], vz = vel[i*3+2];
  float v2x = vx;
  float v2y = vy + DT*(-9.81f);
  float v2z = vz;
  float px = pos[i*3+0] + (DT*(v2x+vx))*0.5f;
  float py = pos[i*3+1] + (DT*(v2y+vy))*0.5f;
  float pz = pos[i*3+2] + (DT*(v2z+vz))*0.5f;
  pos2[i*3+0]=px; pos2[i*3+1]=py; pos2[i*3+2]=pz;
  feats4[i*4+0]=1.f; feats4[i*4+1]=v2x; feats4[i*4+2]=v2y; feats4[i*4+3]=v2z;
}

// ---------------- geometry: per (n,k) 8 corner weights + bins ----------------
__global__ __launch_bounds__(256) void k_geom(const float* __restrict__ pos2, const int* __restrict__ nbrs,
                                              float* __restrict__ gw, unsigned char* __restrict__ gb){
  int idx = blockIdx.x*256 + threadIdx.x;   // < NP*KN
  int n = idx >> 5;
  int nbr = nbrs[idx];
  const float R = 0.5f * (float)(1.5*6.0*0.025);
  float x = (pos2[nbr*3+0]-pos2[n*3+0])/R;
  float y = (pos2[nbr*3+1]-pos2[n*3+1])/R;
  float z = (pos2[nbr*3+2]-pos2[n*3+2])/R;
  float sq = x*x+y*y+z*z;
  float w = 0.f;
  if (sq < 1.f){ float t1 = 1.f-sq; w = t1*t1*t1; }
  if (nbr == n) w = 0.f;     // exclude_self
  const float eps = 1e-8f;
  float norm = sqrtf(sq);
  float sq_xy = x*x+y*y;
  bool polar = 1.25f*z*z > sq_xy;
  float sa = sqrtf(3.f*norm/(norm+fabsf(z)+eps));
  float sb = norm/(sqrtf(sq_xy)+eps);
  float xc = polar ? x*sa : x*sb;
  float yc = polar ? y*sa : y*sb;
  float zc = polar ? sgnf(z)*norm : 1.5f*z;
  if (sq < eps){ xc=x; yc=y; zc=z; }
  float nxy = sqrtf(xc*xc+yc*yc);
  const float fo_pi = (float)(4.0/3.141592653589793);
  float sx = (fabsf(xc)>eps) ? xc : eps;
  float sy = (fabsf(yc)>eps) ? yc : eps;
  float ux = sgnf(xc)*nxy;
  float vv = sgnf(yc)*nxy;
  bool xbig = fabsf(yc) <= fabsf(xc);
  float u = xbig ? ux : vv*fo_pi*atanf(xc/sy);
  float v = xbig ? ux*fo_pi*atanf(yc/sx) : vv;
  if (nxy < eps){ u = xc; v = yc; }
  float tx = fminf(fmaxf((u  + 1.f)*1.5f, 0.f), 3.f);
  float ty = fminf(fmaxf((v  + 1.f)*1.5f, 0.f), 3.f);
  float tz = fminf(fmaxf((zc + 1.f)*1.5f, 0.f), 3.f);
  int ix = (int)floorf(tx); ix = ix>2?2:ix;
  int iy = (int)floorf(ty); iy = iy>2?2:iy;
  int iz = (int)floorf(tz); iz = iz>2?2:iz;
  float fx = tx-(float)ix, fy = ty-(float)iy, fz = tz-(float)iz;
  float wxa[2] = {1.f-fx, fx};
  float wya[2] = {1.f-fy, fy};
  float wza[2] = {1.f-fz, fz};
  #pragma unroll
  for (int cc=0; cc<8; cc++){
    int cx = cc>>2, cy = (cc>>1)&1, cz = cc&1;
    gw[idx*8+cc] = w * wxa[cx]*wya[cy]*wza[cz];
    gb[idx*8+cc] = (unsigned char)((ix+cx)*16 + (iy+cy)*4 + (iz+cz));
  }
}

// ---------------- cconv0: Cin=4 -> Cout=32, 16 queries/wg ----------------
__global__ __launch_bounds__(256) void k_cconv0(const float* __restrict__ feats4, const int* __restrict__ nbrs,
    const float* __restrict__ gw, const unsigned char* __restrict__ gb,
    const float* __restrict__ W0, const float* __restrict__ b0, float* __restrict__ a0f){
  __shared__ float Bs[16*256];   // 16 q x 64 bins x 4 cin
  __shared__ float Ws[8192];     // full W0
  int t = threadIdx.x;
  int qbase = blockIdx.x*16;
  #pragma unroll
  for (int i=0;i<16;i++) Bs[i*256+t]=0.f;
  #pragma unroll
  for (int i=0;i<32;i++) Ws[i*256+t]=W0[i*256+t];
  __syncthreads();
  {
    int c = t&3, sub = t>>2;
    int q = sub>>2, k0 = (sub&3)*8;
    for (int i=0;i<8;i++){
      int idx = (qbase+q)*KN + k0 + i;
      int nbr = nbrs[idx];
      float f = feats4[nbr*4+c];
      #pragma unroll
      for (int cc=0;cc<8;cc++){
        float wgt = gw[idx*8+cc];
        if (wgt != 0.f){
          int bin = gb[idx*8+cc];
          atomicAdd(&Bs[q*256 + bin*4 + c], wgt*f);
        }
      }
    }
  }
  __syncthreads();
  int co = t&31, qq = t>>5;
  for (int qi=0;qi<2;qi++){
    int q = qq*2+qi;
    float acc = b0[co];
    #pragma unroll 8
    for (int kk=0;kk<256;kk++) acc += Bs[q*256+kk]*Ws[kk*32+co];
    a0f[(qbase+q)*32+co] = acc;
  }
}

// ---------------- LN(a0f) twice + Q1,K1,V1 (selfW) and Q2 (srcW) ----------------
__global__ __launch_bounds__(128) void k_lnproj1(const float* __restrict__ a0f,
    const float* __restrict__ lna, const float* __restrict__ lnb,
    const float* __restrict__ selfW, const float* __restrict__ selfb,
    const float* __restrict__ srcW, const float* __restrict__ srcb,
    float* __restrict__ Q1, float* __restrict__ K1o, float* __restrict__ V1, float* __restrict__ Q2){
  __shared__ float sh[4][2][32];
  int t=threadIdx.x, rr=t>>5, c=t&31;
  int r = blockIdx.x*4+rr;
  float x = a0f[r*32+c];
  float s = x;
  for (int o=16;o;o>>=1) s += __shfl_xor(s,o,32);
  float mu = s*(1.f/32.f);
  float d = x-mu;
  float s2 = d*d;
  for (int o=16;o;o>>=1) s2 += __shfl_xor(s2,o,32);
  float istd = 1.f/(sqrtf(s2*(1.f/31.f))+1e-6f);
  sh[rr][0][c] = lna[c]*d*istd + lnb[c];
  sh[rr][1][c] = lna[32+c]*d*istd + lnb[32+c];
  __syncthreads();
  float aq = selfb[c], ak = selfb[32+c], av = selfb[64+c], aq2 = srcb[c];
  for (int cc=0;cc<32;cc++){
    float v0 = sh[rr][0][cc], v1 = sh[rr][1][cc];
    aq  += v0*selfW[cc*32+c];
    ak  += v0*selfW[1024+cc*32+c];
    av  += v0*selfW[2048+cc*32+c];
    aq2 += v1*srcW[cc*32+c];
  }
  Q1[r*32+c]=aq; K1o[r*32+c]=ak; V1[r*32+c]=av; Q2[r*32+c]=aq2;
}

// ---------------- attention partials: 64 queries x 512 keys per 1-wave block ----------------
__global__ __launch_bounds__(64) void k_attn_part(const float* __restrict__ Q, const float* __restrict__ Km,
    const float* __restrict__ Vm, float* __restrict__ Pacc, float* __restrict__ Pml){
  __shared__ float Ks[32*32];
  __shared__ float Vs[32*32];
  int lane = threadIdx.x;
  int qb = blockIdx.x, kp = blockIdx.y;
  int q = qb*64 + lane;
  float qr[32];
  #pragma unroll
  for (int d=0; d<8; d++){
    float4 v = *(const float4*)(Q + q*32 + d*4);
    qr[d*4+0]=v.x; qr[d*4+1]=v.y; qr[d*4+2]=v.z; qr[d*4+3]=v.w;
  }
  float m = -1e30f, l = 0.f;
  float acc[32];
  #pragma unroll
  for (int d=0;d<32;d++) acc[d]=0.f;
  int row = lane>>1, colb = (lane&1)*16;
  for (int ch=0; ch<16; ch++){
    int kb = kp*512 + ch*32;
    #pragma unroll
    for (int i=0;i<4;i++){
      *(float4*)&Ks[row*32+colb+i*4] = *(const float4*)(Km + (kb+row)*32 + colb + i*4);
      *(float4*)&Vs[row*32+colb+i*4] = *(const float4*)(Vm + (kb+row)*32 + colb + i*4);
    }
    __syncthreads();
    float s[32];
    #pragma unroll
    for (int j=0;j<32;j++){
      float sv = 0.f;
      #pragma unroll
      for (int d=0;d<32;d++) sv += qr[d]*Ks[j*32+d];
      s[j] = sv * 0.17677669529663687f;   // 1/sqrt(32)
    }
    float cm = s[0];
    #pragma unroll
    for (int j=1;j<32;j++) cm = fmaxf(cm, s[j]);
    float mn = fmaxf(m, cm);
    float corr = expf(m - mn);
    l *= corr;
    #pragma unroll
    for (int d=0;d<32;d++) acc[d] *= corr;
    #pragma unroll
    for (int j=0;j<32;j++){
      float p = expf(s[j]-mn);
      l += p;
      #pragma unroll
      for (int d=0;d<32;d++) acc[d] += p*Vs[j*32+d];
    }
    m = mn;
    __syncthreads();
  }
  int pi = q*16 + kp;
  Pml[pi*2+0]=m; Pml[pi*2+1]=l;
  #pragma unroll
  for (int d=0;d<8;d++){
    float4 v; v.x=acc[d*4]; v.y=acc[d*4+1]; v.z=acc[d*4+2]; v.w=acc[d*4+3];
    *(float4*)(Pacc + pi*32 + d*4) = v;
  }
}

// ---------------- merge partials + out-proj + residual(a0f) ----------------
__global__ __launch_bounds__(128) void k_merge(const float* __restrict__ Pacc, const float* __restrict__ Pml,
    const float* __restrict__ resid, const float* __restrict__ Wo, const float* __restrict__ bo,
    float* __restrict__ outp){
  __shared__ float sh[4][32];
  int t=threadIdx.x, rr=t>>5, c=t&31;
  int r = blockIdx.x*4+rr;
  float m = -1e30f;
  for (int p=0;p<16;p++) m = fmaxf(m, Pml[(r*16+p)*2]);
  float l = 0.f, a = 0.f;
  for (int p=0;p<16;p++){
    float mp = Pml[(r*16+p)*2], lp = Pml[(r*16+p)*2+1];
    float sc = expf(mp-m);
    l += lp*sc;
    a += Pacc[(r*16+p)*32+c]*sc;
  }
  sh[rr][c] = a/l;
  __syncthreads();
  float acc = bo[c];
  for (int cc=0;cc<32;cc++) acc += sh[rr][cc]*Wo[cc*32+c];
  outp[r*32+c] = resid[r*32+c] + acc;
}

// ---------------- K2,V2 = h1 @ srcW[1],srcW[2] ----------------
__global__ __launch_bounds__(128) void k_projkv(const float* __restrict__ h1,
    const float* __restrict__ srcW, const float* __restrict__ srcb,
    float* __restrict__ K2, float* __restrict__ V2){
  __shared__ float sh[4][32];
  int t=threadIdx.x, rr=t>>5, c=t&31;
  int r = blockIdx.x*4+rr;
  sh[rr][c] = h1[r*32+c];
  __syncthreads();
  float ak = srcb[32+c], av = srcb[64+c];
  for (int cc=0;cc<32;cc++){
    float v = sh[rr][cc];
    ak += v*srcW[1024+cc*32+c];
    av += v*srcW[2048+cc*32+c];
  }
  K2[r*32+c]=ak; V2[r*32+c]=av;
}

// ---------------- LN(h2) + FFN 32->64->64 ----------------
__global__ __launch_bounds__(128) void k_lnffn(const float* __restrict__ h2,
    const float* __restrict__ lna, const float* __restrict__ lnb,
    const float* __restrict__ w1, const float* __restrict__ b1,
    const float* __restrict__ w2, const float* __restrict__ b2, float* __restrict__ x0){
  __shared__ float sh[4][32];
  __shared__ float sh2[4][64];
  int t=threadIdx.x, rr=t>>5, c=t&31;
  int r = blockIdx.x*4+rr;
  float x = h2[r*32+c];
  float s = x;
  for (int o=16;o;o>>=1) s += __shfl_xor(s,o,32);
  float mu = s*(1.f/32.f);
  float d = x-mu;
  float s2 = d*d;
  for (int o=16;o;o>>=1) s2 += __shfl_xor(s2,o,32);
  float istd = 1.f/(sqrtf(s2*(1.f/31.f))+1e-6f);
  sh[rr][c] = lna[64+c]*d*istd + lnb[64+c];
  __syncthreads();
  #pragma unroll
  for (int jj=0;jj<2;jj++){
    int j = c + jj*32;
    float h = b1[j];
    for (int cc=0;cc<32;cc++) h += sh[rr][cc]*w1[cc*64+j];
    sh2[rr][j] = fmaxf(h, 0.f);
  }
  __syncthreads();
  #pragma unroll
  for (int jj=0;jj<2;jj++){
    int j = c + jj*32;
    float o = b2[j];
    for (int kk=0;kk<64;kk++) o += sh2[rr][kk]*w2[kk*64+j];
    x0[r*64+j] = o;
  }
}

// ---------------- big cconv layer: Cin=Cout=64, + dense + bias + residual ----------------
__global__ __launch_bounds__(256) void k_cconvbig(const float* __restrict__ xin, const int* __restrict__ nbrs,
    const float* __restrict__ gw, const unsigned char* __restrict__ gb,
    const float* __restrict__ W, const float* __restrict__ cb,
    const float* __restrict__ dw, const float* __restrict__ db, float* __restrict__ xout){
  extern __shared__ float smem[];
  float* Bs = smem;            // 8*4096 floats = 128 KB
  float* Wc = smem + 32768;    // 2 x 2048 floats = 16 KB (double buffer)
  int t = threadIdx.x;
  int qbase = blockIdx.x*8;
  #pragma unroll
  for (int i=0;i<32;i++){
    *(float4*)&Bs[(i*256+t)*4] = make_float4(0.f,0.f,0.f,0.f);
  }
  __syncthreads();
  {
    int c = t&63, sub = t>>6;
    for (int q=0;q<8;q++){
      for (int kk=0;kk<8;kk++){
        int idx = (qbase+q)*KN + sub*8 + kk;
        int nbr = nbrs[idx];
        float f = fmaxf(xin[nbr*64+c], 0.f);   // relu on input feats
        #pragma unroll
        for (int cc=0;cc<8;cc++){
          float wgt = gw[idx*8+cc];
          if (wgt != 0.f){
            int bin = gb[idx*8+cc];
            atomicAdd(&Bs[q*4096 + bin*64 + c], wgt*f);
          }
        }
      }
    }
  }
  __syncthreads();
  int qq = t>>5, cop = t&31;
  float acc0 = 0.f, acc1 = 0.f;
  float st[8];
  #pragma unroll
  for (int i=0;i<8;i++) st[i] = W[i*256+t];
  int cur = 0;
  for (int ch=0; ch<128; ch++){
    #pragma unroll
    for (int i=0;i<8;i++) Wc[cur*2048 + i*256 + t] = st[i];
    __syncthreads();
    if (ch < 127){
      #pragma unroll
      for (int i=0;i<8;i++) st[i] = W[(ch+1)*2048 + i*256 + t];
    }
    const float* Bq = Bs + qq*4096 + ch*32;
    const float* Wb = Wc + cur*2048 + cop*2;
    #pragma unroll
    for (int g=0; g<8; g++){
      float4 b4 = *(const float4*)(Bq + g*4);
      float2 w0 = *(const float2*)(Wb + (g*4+0)*64);
      float2 w1 = *(const float2*)(Wb + (g*4+1)*64);
      float2 w2 = *(const float2*)(Wb + (g*4+2)*64);
      float2 w3 = *(const float2*)(Wb + (g*4+3)*64);
      acc0 += b4.x*w0.x; acc1 += b4.x*w0.y;
      acc0 += b4.y*w1.x; acc1 += b4.y*w1.y;
      acc0 += b4.z*w2.x; acc1 += b4.z*w2.y;
      acc0 += b4.w*w3.x; acc1 += b4.w*w3.y;
    }
    cur ^= 1;
  }
  int n = qbase + qq;
  int co0 = cop*2;
  for (int cc=0; cc<64; cc++){
    float iv = fmaxf(xin[n*64+cc], 0.f);
    float2 dv = *(const float2*)(dw + cc*64 + co0);
    acc0 += iv*dv.x; acc1 += iv*dv.y;
  }
  acc0 += cb[co0]   + db[co0];
  acc1 += cb[co0+1] + db[co0+1];
  float r0 = xin[n*64+co0], r1 = xin[n*64+co0+1];  // residual (pre-relu x)
  xout[n*64+co0]   = acc0 + r0;
  xout[n*64+co0+1] = acc1 + r1;
}

// ---------------- final cconv layer: Cout=3, + dense + epilogue ----------------
__global__ __launch_bounds__(256) void k_cconvfinal(const float* __restrict__ xin, const int* __restrict__ nbrs,
    const float* __restrict__ gw, const unsigned char* __restrict__ gb,
    const float* __restrict__ W3, const float* __restrict__ cb3,
    const float* __restrict__ dw3, const float* __restrict__ db3,
    const float* __restrict__ pos, const float* __restrict__ pos2, float* __restrict__ outp){
  extern __shared__ float smem[];
  float* Bs = smem;            // 8*4096
  float* red = smem + 32768;   // 192
  int t = threadIdx.x;
  int qbase = blockIdx.x*8;
  #pragma unroll
  for (int i=0;i<32;i++){
    *(float4*)&Bs[(i*256+t)*4] = make_float4(0.f,0.f,0.f,0.f);
  }
  __syncthreads();
  {
    int c = t&63, sub = t>>6;
    for (int q=0;q<8;q++){
      for (int kk=0;kk<8;kk++){
        int idx = (qbase+q)*KN + sub*8 + kk;
        int nbr = nbrs[idx];
        float f = fmaxf(xin[nbr*64+c], 0.f);
        #pragma unroll
        for (int cc=0;cc<8;cc++){
          float wgt = gw[idx*8+cc];
          if (wgt != 0.f){
            int bin = gb[idx*8+cc];
            atomicAdd(&Bs[q*4096 + bin*64 + c], wgt*f);
          }
        }
      }
    }
  }
  __syncthreads();
  if (t < 192){
    int q = t/24, rem = t%24, part = rem/3, co = rem%3;
    float acc = 0.f;
    int k0 = part*512;
    #pragma unroll 4
    for (int kk=0; kk<512; kk++) acc += Bs[q*4096 + k0+kk]*W3[(k0+kk)*3+co];
    red[t] = acc;
  }
  __syncthreads();
  if (t < 24){
    int q = t/3, co = t%3;
    int n = qbase+q;
    float y = cb3[co] + db3[co];
    #pragma unroll
    for (int p=0;p<8;p++) y += red[q*24 + p*3 + co];
    for (int cc=0; cc<64; cc++) y += fmaxf(xin[n*64+cc],0.f)*dw3[cc*3+co];
    float pc = y*(1.f/128.f);
    float po = pos2[n*3+co] + pc;
    outp[n*3+co] = po;
    outp[NP*3 + n*3+co] = (po - pos[n*3+co]) / 0.02f;
  }
}

extern "C" void kernel_launch(void* const* d_in, const int* in_sizes, int n_in,
                              void* d_out, int out_size, void* d_ws, size_t ws_size,
                              hipStream_t stream) {
  const float* pos   = (const float*)d_in[0];
  const float* vel   = (const float*)d_in[1];
  const int*   fn    = (const int*)d_in[4];
  const float* cw0f  = (const float*)d_in[6];
  const float* cb0f  = (const float*)d_in[7];
  const float* cw1   = (const float*)d_in[10];
  const float* cb1   = (const float*)d_in[11];
  const float* cw2   = (const float*)d_in[12];
  const float* cb2   = (const float*)d_in[13];
  const float* cw3   = (const float*)d_in[14];
  const float* cb3   = (const float*)d_in[15];
  const float* dw1   = (const float*)d_in[16];
  const float* db1   = (const float*)d_in[17];
  const float* dw2   = (const float*)d_in[18];
  const float* db2   = (const float*)d_in[19];
  const float* dw3   = (const float*)d_in[20];
  const float* db3   = (const float*)d_in[21];
  const float* selfW = (const float*)d_in[22];
  const float* selfb = (const float*)d_in[23];
  const float* srcW  = (const float*)d_in[24];
  const float* srcb  = (const float*)d_in[25];
  const float* lna   = (const float*)d_in[26];
  const float* lnb   = (const float*)d_in[27];
  const float* ffw1  = (const float*)d_in[28];
  const float* ffb1  = (const float*)d_in[29];
  const float* ffw2  = (const float*)d_in[30];
  const float* ffb2  = (const float*)d_in[31];

  float* ws = (float*)d_ws;
  float* pos2   = ws + 0;          // 24576
  float* feats4 = ws + 24576;      // 32768
  float* a0f    = ws + 57344;      // 262144
  float* Q1     = ws + 319488;     // 262144
  float* K1     = ws + 581632;     // 262144
  float* V1     = ws + 843776;     // 262144
  float* Q2     = ws + 1105920;    // 262144
  float* h1     = ws + 1368064;    // 262144
  float* K2     = ws + 1630208;    // 262144
  float* V2     = ws + 1892352;    // 262144
  float* h2     = ws + 2154496;    // 262144
  float* Pacc   = ws + 2416640;    // 4194304
  float* Pml    = ws + 6610944;    // 262144
  float* x0     = ws + 6873088;    // 524288
  float* x1     = ws + 7397376;    // 524288
  float* x2     = ws + 7921664;    // 524288 -> ends 8445952
  float* gw     = ws + 8445952;    // 2097152 -> ends 10543104
  unsigned char* gb = (unsigned char*)(ws + 10543104);  // 2 MB; total ~44.3 MB

  float* outp = (float*)d_out;

  hipFuncSetAttribute(reinterpret_cast<const void*>(k_cconvbig),
                      hipFuncAttributeMaxDynamicSharedMemorySize, 147456);
  hipFuncSetAttribute(reinterpret_cast<const void*>(k_cconvfinal),
                      hipFuncAttributeMaxDynamicSharedMemorySize, 131840);

  k_prep<<<NP/256, 256, 0, stream>>>(pos, vel, pos2, feats4);
  k_geom<<<NP*KN/256, 256, 0, stream>>>(pos2, fn, gw, gb);
  k_cconv0<<<NP/16, 256, 0, stream>>>(feats4, fn, gw, gb, cw0f, cb0f, a0f);
  k_lnproj1<<<NP/4, 128, 0, stream>>>(a0f, lna, lnb, selfW, selfb, srcW, srcb, Q1, K1, V1, Q2);
  k_attn_part<<<dim3(NP/64, 16), 64, 0, stream>>>(Q1, K1, V1, Pacc, Pml);
  k_merge<<<NP/4, 128, 0, stream>>>(Pacc, Pml, a0f, selfW+3072, selfb+96, h1);
  k_projkv<<<NP/4, 128, 0, stream>>>(h1, srcW, srcb, K2, V2);
  k_attn_part<<<dim3(NP/64, 16), 64, 0, stream>>>(Q2, K2, V2, Pacc, Pml);
  k_merge<<<NP/4, 128, 0, stream>>>(Pacc, Pml, a0f, srcW+3072, srcb+96, h2);
  k_lnffn<<<NP/4, 128, 0, stream>>>(h2, lna, lnb, ffw1, ffb1, ffw2, ffb2, x0);
  k_cconvbig<<<NP/8, 256, 147456, stream>>>(x0, fn, gw, gb, cw1, cb1, dw1, db1, x1);
  k_cconvbig<<<NP/8, 256, 147456, stream>>>(x1, fn, gw, gb, cw2, cb2, dw2, db2, x2);
  k_cconvfinal<<<NP/8, 256, 131840, stream>>>(x2, fn, gw, gb, cw3, cb3, dw3, db3, pos, pos2, outp);
}

// Round 2
// 2114.596 us; speedup vs baseline: 1.0696x; 1.0696x over previous
//
#include <hip/hip_runtime.h>
#include <math.h>

#define NP 8192
#define KN 32

__device__ __forceinline__ float sgnf(float x){ return (x>0.f)?1.f:((x<0.f)?-1.f:0.f); }

// swizzled B index: base q*4096 + k, XOR bank-spread (consistent across scatter + both GEMMs)
__device__ __forceinline__ int bswz(int q, int k){
  return q*4096 + (k ^ ((q&7)<<2) ^ (((k>>6)&3)<<3));
}

// ---------------- prep: pos2, vel2, feats4 ----------------
__global__ __launch_bounds__(256) void k_prep(const float* __restrict__ pos, const float* __restrict__ vel,
                                              float* __restrict__ pos2, float* __restrict__ feats4){
  int i = blockIdx.x*256 + threadIdx.x;
  const float DT = 0.02f;
  float vx = vel[i*3+0], vy = vel[i*3+1], vz = vel[i*3+2];
  float v2x = vx;
  float v2y = vy + DT*(-9.81f);
  float v2z = vz;
  float px = pos[i*3+0] + (DT*(v2x+vx))*0.5f;
  float py = pos[i*3+1] + (DT*(v2y+vy))*0.5f;
  float pz = pos[i*3+2] + (DT*(v2z+vz))*0.5f;
  pos2[i*3+0]=px; pos2[i*3+1]=py; pos2[i*3+2]=pz;
  feats4[i*4+0]=1.f; feats4[i*4+1]=v2x; feats4[i*4+2]=v2y; feats4[i*4+3]=v2z;
}

// ---------------- geometry: per (n,k) 8 corner weights + bins ----------------
__global__ __launch_bounds__(256) void k_geom(const float* __restrict__ pos2, const int* __restrict__ nbrs,
                                              float* __restrict__ gw, unsigned char* __restrict__ gb){
  int idx = blockIdx.x*256 + threadIdx.x;   // < NP*KN
  int n = idx >> 5;
  int nbr = nbrs[idx];
  const float R = 0.5f * (float)(1.5*6.0*0.025);
  float x = (pos2[nbr*3+0]-pos2[n*3+0])/R;
  float y = (pos2[nbr*3+1]-pos2[n*3+1])/R;
  float z = (pos2[nbr*3+2]-pos2[n*3+2])/R;
  float sq = x*x+y*y+z*z;
  float w = 0.f;
  if (sq < 1.f){ float t1 = 1.f-sq; w = t1*t1*t1; }
  if (nbr == n) w = 0.f;     // exclude_self
  const float eps = 1e-8f;
  float norm = sqrtf(sq);
  float sq_xy = x*x+y*y;
  bool polar = 1.25f*z*z > sq_xy;
  float sa = sqrtf(3.f*norm/(norm+fabsf(z)+eps));
  float sb = norm/(sqrtf(sq_xy)+eps);
  float xc = polar ? x*sa : x*sb;
  float yc = polar ? y*sa : y*sb;
  float zc = polar ? sgnf(z)*norm : 1.5f*z;
  if (sq < eps){ xc=x; yc=y; zc=z; }
  float nxy = sqrtf(xc*xc+yc*yc);
  const float fo_pi = (float)(4.0/3.141592653589793);
  float sx = (fabsf(xc)>eps) ? xc : eps;
  float sy = (fabsf(yc)>eps) ? yc : eps;
  float ux = sgnf(xc)*nxy;
  float vv = sgnf(yc)*nxy;
  bool xbig = fabsf(yc) <= fabsf(xc);
  float u = xbig ? ux : vv*fo_pi*atanf(xc/sy);
  float v = xbig ? ux*fo_pi*atanf(yc/sx) : vv;
  if (nxy < eps){ u = xc; v = yc; }
  float tx = fminf(fmaxf((u  + 1.f)*1.5f, 0.f), 3.f);
  float ty = fminf(fmaxf((v  + 1.f)*1.5f, 0.f), 3.f);
  float tz = fminf(fmaxf((zc + 1.f)*1.5f, 0.f), 3.f);
  int ix = (int)floorf(tx); ix = ix>2?2:ix;
  int iy = (int)floorf(ty); iy = iy>2?2:iy;
  int iz = (int)floorf(tz); iz = iz>2?2:iz;
  float fx = tx-(float)ix, fy = ty-(float)iy, fz = tz-(float)iz;
  float wxa[2] = {1.f-fx, fx};
  float wya[2] = {1.f-fy, fy};
  float wza[2] = {1.f-fz, fz};
  #pragma unroll
  for (int cc=0; cc<8; cc++){
    int cx = cc>>2, cy = (cc>>1)&1, cz = cc&1;
    gw[idx*8+cc] = w * wxa[cx]*wya[cy]*wza[cz];
    gb[idx*8+cc] = (unsigned char)((ix+cx)*16 + (iy+cy)*4 + (iz+cz));
  }
}

// ---------------- cconv0: Cin=4 -> Cout=32, 16 queries/wg ----------------
__global__ __launch_bounds__(256) void k_cconv0(const float* __restrict__ feats4, const int* __restrict__ nbrs,
    const float* __restrict__ gw, const unsigned char* __restrict__ gb,
    const float* __restrict__ W0, const float* __restrict__ b0, float* __restrict__ a0f){
  __shared__ float Bs[16*256];   // 16 q x 64 bins x 4 cin
  __shared__ float Ws[8192];     // full W0
  int t = threadIdx.x;
  int qbase = blockIdx.x*16;
  #pragma unroll
  for (int i=0;i<16;i++) Bs[i*256+t]=0.f;
  #pragma unroll
  for (int i=0;i<32;i++) Ws[i*256+t]=W0[i*256+t];
  __syncthreads();
  {
    int c = t&3, sub = t>>2;
    int q = sub>>2, k0 = (sub&3)*8;
    for (int i=0;i<8;i++){
      int idx = (qbase+q)*KN + k0 + i;
      int nbr = nbrs[idx];
      float f = feats4[nbr*4+c];
      #pragma unroll
      for (int cc=0;cc<8;cc++){
        float wgt = gw[idx*8+cc];
        if (wgt != 0.f){
          int bin = gb[idx*8+cc];
          atomicAdd(&Bs[q*256 + bin*4 + c], wgt*f);
        }
      }
    }
  }
  __syncthreads();
  int co = t&31, qq = t>>5;
  for (int qi=0;qi<2;qi++){
    int q = qq*2+qi;
    float acc = b0[co];
    #pragma unroll 8
    for (int kk=0;kk<256;kk++) acc += Bs[q*256+kk]*Ws[kk*32+co];
    a0f[(qbase+q)*32+co] = acc;
  }
}

// ---------------- LN(a0f) twice + Q1,K1,V1 (selfW) and Q2 (srcW) ----------------
__global__ __launch_bounds__(128) void k_lnproj1(const float* __restrict__ a0f,
    const float* __restrict__ lna, const float* __restrict__ lnb,
    const float* __restrict__ selfW, const float* __restrict__ selfb,
    const float* __restrict__ srcW, const float* __restrict__ srcb,
    float* __restrict__ Q1, float* __restrict__ K1o, float* __restrict__ V1, float* __restrict__ Q2){
  __shared__ float sh[4][2][32];
  int t=threadIdx.x, rr=t>>5, c=t&31;
  int r = blockIdx.x*4+rr;
  float x = a0f[r*32+c];
  float s = x;
  for (int o=16;o;o>>=1) s += __shfl_xor(s,o,32);
  float mu = s*(1.f/32.f);
  float d = x-mu;
  float s2 = d*d;
  for (int o=16;o;o>>=1) s2 += __shfl_xor(s2,o,32);
  float istd = 1.f/(sqrtf(s2*(1.f/31.f))+1e-6f);
  sh[rr][0][c] = lna[c]*d*istd + lnb[c];
  sh[rr][1][c] = lna[32+c]*d*istd + lnb[32+c];
  __syncthreads();
  float aq = selfb[c], ak = selfb[32+c], av = selfb[64+c], aq2 = srcb[c];
  for (int cc=0;cc<32;cc++){
    float v0 = sh[rr][0][cc], v1 = sh[rr][1][cc];
    aq  += v0*selfW[cc*32+c];
    ak  += v0*selfW[1024+cc*32+c];
    av  += v0*selfW[2048+cc*32+c];
    aq2 += v1*srcW[cc*32+c];
  }
  Q1[r*32+c]=aq; K1o[r*32+c]=ak; V1[r*32+c]=av; Q2[r*32+c]=aq2;
}

// ---------------- attention partials: 64 queries x 512 keys per 1-wave block ----------------
__global__ __launch_bounds__(64) void k_attn_part(const float* __restrict__ Q, const float* __restrict__ Km,
    const float* __restrict__ Vm, float* __restrict__ Pacc, float* __restrict__ Pml){
  __shared__ float Ks[32*32];
  __shared__ float Vs[32*32];
  int lane = threadIdx.x;
  int qb = blockIdx.x, kp = blockIdx.y;
  int q = qb*64 + lane;
  float qr[32];
  #pragma unroll
  for (int d=0; d<8; d++){
    float4 v = *(const float4*)(Q + q*32 + d*4);
    qr[d*4+0]=v.x; qr[d*4+1]=v.y; qr[d*4+2]=v.z; qr[d*4+3]=v.w;
  }
  float m = -1e30f, l = 0.f;
  float acc[32];
  #pragma unroll
  for (int d=0;d<32;d++) acc[d]=0.f;
  int row = lane>>1, colb = (lane&1)*16;
  for (int ch=0; ch<16; ch++){
    int kb = kp*512 + ch*32;
    #pragma unroll
    for (int i=0;i<4;i++){
      *(float4*)&Ks[row*32+colb+i*4] = *(const float4*)(Km + (kb+row)*32 + colb + i*4);
      *(float4*)&Vs[row*32+colb+i*4] = *(const float4*)(Vm + (kb+row)*32 + colb + i*4);
    }
    __syncthreads();
    float s[32];
    #pragma unroll
    for (int j=0;j<32;j++){
      float sv = 0.f;
      #pragma unroll
      for (int d=0;d<32;d++) sv += qr[d]*Ks[j*32+d];
      s[j] = sv * 0.17677669529663687f;   // 1/sqrt(32)
    }
    float cm = s[0];
    #pragma unroll
    for (int j=1;j<32;j++) cm = fmaxf(cm, s[j]);
    float mn = fmaxf(m, cm);
    float corr = expf(m - mn);
    l *= corr;
    #pragma unroll
    for (int d=0;d<32;d++) acc[d] *= corr;
    #pragma unroll
    for (int j=0;j<32;j++){
      float p = expf(s[j]-mn);
      l += p;
      #pragma unroll
      for (int d=0;d<32;d++) acc[d] += p*Vs[j*32+d];
    }
    m = mn;
    __syncthreads();
  }
  int pi = q*16 + kp;
  Pml[pi*2+0]=m; Pml[pi*2+1]=l;
  #pragma unroll
  for (int d=0;d<8;d++){
    float4 v; v.x=acc[d*4]; v.y=acc[d*4+1]; v.z=acc[d*4+2]; v.w=acc[d*4+3];
    *(float4*)(Pacc + pi*32 + d*4) = v;
  }
}

// ---------------- merge partials + out-proj + residual(a0f) ----------------
__global__ __launch_bounds__(128) void k_merge(const float* __restrict__ Pacc, const float* __restrict__ Pml,
    const float* __restrict__ resid, const float* __restrict__ Wo, const float* __restrict__ bo,
    float* __restrict__ outp){
  __shared__ float sh[4][32];
  int t=threadIdx.x, rr=t>>5, c=t&31;
  int r = blockIdx.x*4+rr;
  float m = -1e30f;
  for (int p=0;p<16;p++) m = fmaxf(m, Pml[(r*16+p)*2]);
  float l = 0.f, a = 0.f;
  for (int p=0;p<16;p++){
    float mp = Pml[(r*16+p)*2], lp = Pml[(r*16+p)*2+1];
    float sc = expf(mp-m);
    l += lp*sc;
    a += Pacc[(r*16+p)*32+c]*sc;
  }
  sh[rr][c] = a/l;
  __syncthreads();
  float acc = bo[c];
  for (int cc=0;cc<32;cc++) acc += sh[rr][cc]*Wo[cc*32+c];
  outp[r*32+c] = resid[r*32+c] + acc;
}

// ---------------- K2,V2 = h1 @ srcW[1],srcW[2] ----------------
__global__ __launch_bounds__(128) void k_projkv(const float* __restrict__ h1,
    const float* __restrict__ srcW, const float* __restrict__ srcb,
    float* __restrict__ K2, float* __restrict__ V2){
  __shared__ float sh[4][32];
  int t=threadIdx.x, rr=t>>5, c=t&31;
  int r = blockIdx.x*4+rr;
  sh[rr][c] = h1[r*32+c];
  __syncthreads();
  float ak = srcb[32+c], av = srcb[64+c];
  for (int cc=0;cc<32;cc++){
    float v = sh[rr][cc];
    ak += v*srcW[1024+cc*32+c];
    av += v*srcW[2048+cc*32+c];
  }
  K2[r*32+c]=ak; V2[r*32+c]=av;
}

// ---------------- LN(h2) + FFN 32->64->64 ----------------
__global__ __launch_bounds__(128) void k_lnffn(const float* __restrict__ h2,
    const float* __restrict__ lna, const float* __restrict__ lnb,
    const float* __restrict__ w1, const float* __restrict__ b1,
    const float* __restrict__ w2, const float* __restrict__ b2, float* __restrict__ x0){
  __shared__ float sh[4][32];
  __shared__ float sh2[4][64];
  int t=threadIdx.x, rr=t>>5, c=t&31;
  int r = blockIdx.x*4+rr;
  float x = h2[r*32+c];
  float s = x;
  for (int o=16;o;o>>=1) s += __shfl_xor(s,o,32);
  float mu = s*(1.f/32.f);
  float d = x-mu;
  float s2 = d*d;
  for (int o=16;o;o>>=1) s2 += __shfl_xor(s2,o,32);
  float istd = 1.f/(sqrtf(s2*(1.f/31.f))+1e-6f);
  sh[rr][c] = lna[64+c]*d*istd + lnb[64+c];
  __syncthreads();
  #pragma unroll
  for (int jj=0;jj<2;jj++){
    int j = c + jj*32;
    float h = b1[j];
    for (int cc=0;cc<32;cc++) h += sh[rr][cc]*w1[cc*64+j];
    sh2[rr][j] = fmaxf(h, 0.f);
  }
  __syncthreads();
  #pragma unroll
  for (int jj=0;jj<2;jj++){
    int j = c + jj*32;
    float o = b2[j];
    for (int kk=0;kk<64;kk++) o += sh2[rr][kk]*w2[kk*64+j];
    x0[r*64+j] = o;
  }
}

// ---------------- big cconv layer v2: Cin=Cout=64, 8 waves, reg-tiled GEMM ----------------
// LDS: Bs 32768 f32 (swizzled) | WB 4096 f32 (64k x 64co window, swizzled) | Yb 512 f32
__global__ __launch_bounds__(512) void k_cconvbig(const float* __restrict__ xin, const int* __restrict__ nbrs,
    const float* __restrict__ gw, const unsigned char* __restrict__ gb,
    const float* __restrict__ W, const float* __restrict__ cb,
    const float* __restrict__ dw, const float* __restrict__ db, float* __restrict__ xout){
  extern __shared__ float smem[];
  float* Bs = smem;
  float* WB = smem + 32768;
  float* Yb = smem + 36864;
  int t = threadIdx.x;
  int qbase = blockIdx.x*8;
  // zero B accumulators + Y
  #pragma unroll
  for (int i=0;i<16;i++) ((float4*)Bs)[i*512+t] = make_float4(0.f,0.f,0.f,0.f);
  Yb[t] = 0.f;
  __syncthreads();
  // ---- scatter: wave w -> query qbase+w, lane = ci ----
  {
    int w = t>>6, l = t&63;
    int n = qbase + w;
    for (int k=0;k<KN;k++){
      int idx = n*KN + k;
      float4 g0 = *(const float4*)(gw + (size_t)idx*8);
      float4 g1 = *(const float4*)(gw + (size_t)idx*8 + 4);
      float wsum = g0.x+g0.y+g0.z+g0.w+g1.x+g1.y+g1.z+g1.w;
      if (wsum > 0.f){
        int nbr = nbrs[idx];
        float xv = fmaxf(xin[nbr*64 + l], 0.f);
        uint2 gv = *(const uint2*)(gb + (size_t)idx*8);
        float gg[8] = {g0.x,g0.y,g0.z,g0.w,g1.x,g1.y,g1.z,g1.w};
        #pragma unroll
        for (int cc=0;cc<8;cc++){
          unsigned word = (cc<4) ? gv.x : gv.y;
          int bin = (word >> (8*(cc&3))) & 255;
          atomicAdd(&Bs[bswz(w, bin*64 + l)], gg[cc]*xv);
        }
      }
    }
  }
  __syncthreads();
  // ---- GEMM: thread = (cot = t&7 -> 8 co, kp = t>>3 -> 1 k per 64-k window) ----
  int cot = t&7, kp = t>>3;
  int co0 = cot*8;
  float acc[8][8];
  #pragma unroll
  for (int q=0;q<8;q++)
    #pragma unroll
    for (int j=0;j<8;j++) acc[q][j]=0.f;
  // stage-index math (same thread roles for staging): row kl = t>>3, colbase = (t&7)*8
  float4 ldA = ((const float4*)W)[t*2];
  float4 ldB = ((const float4*)W)[t*2+1];
  for (int win=0; win<64; ++win){
    __syncthreads();   // previous window's compute done
    {
      int swz = (kp&3)<<3;
      *(float4*)&WB[kp*64 + (co0 ^ swz)]       = ldA;
      *(float4*)&WB[kp*64 + ((co0+4) ^ swz)]   = ldB;
    }
    if (win < 63){
      ldA = ((const float4*)W)[(win+1)*1024 + t*2];
      ldB = ((const float4*)W)[(win+1)*1024 + t*2+1];
    }
    __syncthreads();   // window staged
    int swz = (kp&3)<<3;
    float4 w0 = *(const float4*)&WB[kp*64 + (co0 ^ swz)];
    float4 w1 = *(const float4*)&WB[kp*64 + ((co0+4) ^ swz)];
    int kidx = win*64 + kp;
    #pragma unroll
    for (int q=0;q<8;q++){
      float bv = Bs[bswz(q, kidx)];
      acc[q][0] += bv*w0.x; acc[q][1] += bv*w0.y; acc[q][2] += bv*w0.z; acc[q][3] += bv*w0.w;
      acc[q][4] += bv*w1.x; acc[q][5] += bv*w1.y; acc[q][6] += bv*w1.z; acc[q][7] += bv*w1.w;
    }
  }
  // ---- reduce over kp via LDS atomics ----
  #pragma unroll
  for (int q=0;q<8;q++)
    #pragma unroll
    for (int j=0;j<8;j++)
      atomicAdd(&Yb[q*64 + co0 + j], acc[q][j]);
  __syncthreads();
  // ---- epilogue: conv + bias + dense + residual ----
  {
    int q = t>>6, co = t&63;
    int n = qbase + q;
    float y = Yb[t] + cb[co] + db[co];
    for (int ci=0; ci<64; ci++){
      y += fmaxf(xin[n*64+ci], 0.f) * dw[ci*64+co];
    }
    xout[n*64+co] = y + xin[n*64+co];
  }
}

// ---------------- final cconv layer v2: Cout=3 ----------------
__global__ __launch_bounds__(512) void k_cconvfinal(const float* __restrict__ xin, const int* __restrict__ nbrs,
    const float* __restrict__ gw, const unsigned char* __restrict__ gb,
    const float* __restrict__ W3, const float* __restrict__ cb3,
    const float* __restrict__ dw3, const float* __restrict__ db3,
    const float* __restrict__ pos, const float* __restrict__ pos2, float* __restrict__ outp){
  extern __shared__ float smem[];
  float* Bs = smem;
  float* Yf = smem + 32768;   // 24 f32
  int t = threadIdx.x;
  int qbase = blockIdx.x*8;
  #pragma unroll
  for (int i=0;i<16;i++) ((float4*)Bs)[i*512+t] = make_float4(0.f,0.f,0.f,0.f);
  if (t < 24) Yf[t] = 0.f;
  __syncthreads();
  // scatter (same as big)
  {
    int w = t>>6, l = t&63;
    int n = qbase + w;
    for (int k=0;k<KN;k++){
      int idx = n*KN + k;
      float4 g0 = *(const float4*)(gw + (size_t)idx*8);
      float4 g1 = *(const float4*)(gw + (size_t)idx*8 + 4);
      float wsum = g0.x+g0.y+g0.z+g0.w+g1.x+g1.y+g1.z+g1.w;
      if (wsum > 0.f){
        int nbr = nbrs[idx];
        float xv = fmaxf(xin[nbr*64 + l], 0.f);
        uint2 gv = *(const uint2*)(gb + (size_t)idx*8);
        float gg[8] = {g0.x,g0.y,g0.z,g0.w,g1.x,g1.y,g1.z,g1.w};
        #pragma unroll
        for (int cc=0;cc<8;cc++){
          unsigned word = (cc<4) ? gv.x : gv.y;
          int bin = (word >> (8*(cc&3))) & 255;
          atomicAdd(&Bs[bswz(w, bin*64 + l)], gg[cc]*xv);
        }
      }
    }
  }
  __syncthreads();
  // gemm: thread (q = t&7, kp = t>>3): 64-k contiguous slice, 3 outputs
  {
    int q = t&7, kp = t>>3;
    float a0=0.f, a1=0.f, a2=0.f;
    #pragma unroll 4
    for (int j=0;j<16;j++){
      int k = kp*64 + j*4;
      float4 b = *(const float4*)&Bs[bswz(q, k)];
      const float* w = W3 + (size_t)k*3;
      a0 += b.x*w[0] + b.y*w[3] + b.z*w[6] + b.w*w[9];
      a1 += b.x*w[1] + b.y*w[4] + b.z*w[7] + b.w*w[10];
      a2 += b.x*w[2] + b.y*w[5] + b.z*w[8] + b.w*w[11];
    }
    atomicAdd(&Yf[q*3+0], a0);
    atomicAdd(&Yf[q*3+1], a1);
    atomicAdd(&Yf[q*3+2], a2);
  }
  __syncthreads();
  if (t < 24){
    int q = t/3, co = t%3;
    int n = qbase + q;
    float y = Yf[t] + cb3[co] + db3[co];
    for (int cc=0; cc<64; cc++) y += fmaxf(xin[n*64+cc],0.f)*dw3[cc*3+co];
    float pc = y*(1.f/128.f);
    float po = pos2[n*3+co] + pc;
    outp[n*3+co] = po;
    outp[NP*3 + n*3+co] = (po - pos[n*3+co]) / 0.02f;
  }
}

extern "C" void kernel_launch(void* const* d_in, const int* in_sizes, int n_in,
                              void* d_out, int out_size, void* d_ws, size_t ws_size,
                              hipStream_t stream) {
  const float* pos   = (const float*)d_in[0];
  const float* vel   = (const float*)d_in[1];
  const int*   fn    = (const int*)d_in[4];
  const float* cw0f  = (const float*)d_in[6];
  const float* cb0f  = (const float*)d_in[7];
  const float* cw1   = (const float*)d_in[10];
  const float* cb1   = (const float*)d_in[11];
  const float* cw2   = (const float*)d_in[12];
  const float* cb2   = (const float*)d_in[13];
  const float* cw3   = (const float*)d_in[14];
  const float* cb3   = (const float*)d_in[15];
  const float* dw1   = (const float*)d_in[16];
  const float* db1   = (const float*)d_in[17];
  const float* dw2   = (const float*)d_in[18];
  const float* db2   = (const float*)d_in[19];
  const float* dw3   = (const float*)d_in[20];
  const float* db3   = (const float*)d_in[21];
  const float* selfW = (const float*)d_in[22];
  const float* selfb = (const float*)d_in[23];
  const float* srcW  = (const float*)d_in[24];
  const float* srcb  = (const float*)d_in[25];
  const float* lna   = (const float*)d_in[26];
  const float* lnb   = (const float*)d_in[27];
  const float* ffw1  = (const float*)d_in[28];
  const float* ffb1  = (const float*)d_in[29];
  const float* ffw2  = (const float*)d_in[30];
  const float* ffb2  = (const float*)d_in[31];

  float* ws = (float*)d_ws;
  float* pos2   = ws + 0;          // 24576
  float* feats4 = ws + 24576;      // 32768
  float* a0f    = ws + 57344;      // 262144
  float* Q1     = ws + 319488;     // 262144
  float* K1     = ws + 581632;     // 262144
  float* V1     = ws + 843776;     // 262144
  float* Q2     = ws + 1105920;    // 262144
  float* h1     = ws + 1368064;    // 262144
  float* K2     = ws + 1630208;    // 262144
  float* V2     = ws + 1892352;    // 262144
  float* h2     = ws + 2154496;    // 262144
  float* Pacc   = ws + 2416640;    // 4194304
  float* Pml    = ws + 6610944;    // 262144
  float* x0     = ws + 6873088;    // 524288
  float* x1     = ws + 7397376;    // 524288
  float* x2     = ws + 7921664;    // 524288 -> ends 8445952
  float* gw     = ws + 8445952;    // 2097152 -> ends 10543104
  unsigned char* gb = (unsigned char*)(ws + 10543104);  // 2 MB

  float* outp = (float*)d_out;

  hipFuncSetAttribute(reinterpret_cast<const void*>(k_cconvbig),
                      hipFuncAttributeMaxDynamicSharedMemorySize, 149504);
  hipFuncSetAttribute(reinterpret_cast<const void*>(k_cconvfinal),
                      hipFuncAttributeMaxDynamicSharedMemorySize, 131168);

  k_prep<<<NP/256, 256, 0, stream>>>(pos, vel, pos2, feats4);
  k_geom<<<NP*KN/256, 256, 0, stream>>>(pos2, fn, gw, gb);
  k_cconv0<<<NP/16, 256, 0, stream>>>(feats4, fn, gw, gb, cw0f, cb0f, a0f);
  k_lnproj1<<<NP/4, 128, 0, stream>>>(a0f, lna, lnb, selfW, selfb, srcW, srcb, Q1, K1, V1, Q2);
  k_attn_part<<<dim3(NP/64, 16), 64, 0, stream>>>(Q1, K1, V1, Pacc, Pml);
  k_merge<<<NP/4, 128, 0, stream>>>(Pacc, Pml, a0f, selfW+3072, selfb+96, h1);
  k_projkv<<<NP/4, 128, 0, stream>>>(h1, srcW, srcb, K2, V2);
  k_attn_part<<<dim3(NP/64, 16), 64, 0, stream>>>(Q2, K2, V2, Pacc, Pml);
  k_merge<<<NP/4, 128, 0, stream>>>(Pacc, Pml, a0f, srcW+3072, srcb+96, h2);
  k_lnffn<<<NP/4, 128, 0, stream>>>(h2, lna, lnb, ffw1, ffb1, ffw2, ffb2, x0);
  k_cconvbig<<<NP/8, 512, 149504, stream>>>(x0, fn, gw, gb, cw1, cb1, dw1, db1, x1);
  k_cconvbig<<<NP/8, 512, 149504, stream>>>(x1, fn, gw, gb, cw2, cb2, dw2, db2, x2);
  k_cconvfinal<<<NP/8, 512, 131168, stream>>>(x2, fn, gw, gb, cw3, cb3, dw3, db3, pos, pos2, outp);
}

// Round 3
// 2046.861 us; speedup vs baseline: 1.1050x; 1.0331x over previous
//
#include <hip/hip_runtime.h>
#include <math.h>

#define NP 8192
#define KN 32

__device__ __forceinline__ float sgnf(float x){ return (x>0.f)?1.f:((x<0.f)?-1.f:0.f); }

// ---------------- prep: pos2, vel2, feats4 ----------------
__global__ __launch_bounds__(256) void k_prep(const float* __restrict__ pos, const float* __restrict__ vel,
                                              float* __restrict__ pos2, float* __restrict__ feats4){
  int i = blockIdx.x*256 + threadIdx.x;
  const float DT = 0.02f;
  float vx = vel[i*3+0], vy = vel[i*3+1], vz = vel[i*3+2];
  float v2x = vx;
  float v2y = vy + DT*(-9.81f);
  float v2z = vz;
  float px = pos[i*3+0] + (DT*(v2x+vx))*0.5f;
  float py = pos[i*3+1] + (DT*(v2y+vy))*0.5f;
  float pz = pos[i*3+2] + (DT*(v2z+vz))*0.5f;
  pos2[i*3+0]=px; pos2[i*3+1]=py; pos2[i*3+2]=pz;
  feats4[i*4+0]=1.f; feats4[i*4+1]=v2x; feats4[i*4+2]=v2y; feats4[i*4+3]=v2z;
}

// ---------------- geometry: per (n,k) 8 corner weights + bins ----------------
__global__ __launch_bounds__(256) void k_geom(const float* __restrict__ pos2, const int* __restrict__ nbrs,
                                              float* __restrict__ gw, unsigned char* __restrict__ gb){
  int idx = blockIdx.x*256 + threadIdx.x;   // < NP*KN
  int n = idx >> 5;
  int nbr = nbrs[idx];
  const float R = 0.5f * (float)(1.5*6.0*0.025);
  float x = (pos2[nbr*3+0]-pos2[n*3+0])/R;
  float y = (pos2[nbr*3+1]-pos2[n*3+1])/R;
  float z = (pos2[nbr*3+2]-pos2[n*3+2])/R;
  float sq = x*x+y*y+z*z;
  float w = 0.f;
  if (sq < 1.f){ float t1 = 1.f-sq; w = t1*t1*t1; }
  if (nbr == n) w = 0.f;     // exclude_self
  const float eps = 1e-8f;
  float norm = sqrtf(sq);
  float sq_xy = x*x+y*y;
  bool polar = 1.25f*z*z > sq_xy;
  float sa = sqrtf(3.f*norm/(norm+fabsf(z)+eps));
  float sb = norm/(sqrtf(sq_xy)+eps);
  float xc = polar ? x*sa : x*sb;
  float yc = polar ? y*sa : y*sb;
  float zc = polar ? sgnf(z)*norm : 1.5f*z;
  if (sq < eps){ xc=x; yc=y; zc=z; }
  float nxy = sqrtf(xc*xc+yc*yc);
  const float fo_pi = (float)(4.0/3.141592653589793);
  float sx = (fabsf(xc)>eps) ? xc : eps;
  float sy = (fabsf(yc)>eps) ? yc : eps;
  float ux = sgnf(xc)*nxy;
  float vv = sgnf(yc)*nxy;
  bool xbig = fabsf(yc) <= fabsf(xc);
  float u = xbig ? ux : vv*fo_pi*atanf(xc/sy);
  float v = xbig ? ux*fo_pi*atanf(yc/sx) : vv;
  if (nxy < eps){ u = xc; v = yc; }
  float tx = fminf(fmaxf((u  + 1.f)*1.5f, 0.f), 3.f);
  float ty = fminf(fmaxf((v  + 1.f)*1.5f, 0.f), 3.f);
  float tz = fminf(fmaxf((zc + 1.f)*1.5f, 0.f), 3.f);
  int ix = (int)floorf(tx); ix = ix>2?2:ix;
  int iy = (int)floorf(ty); iy = iy>2?2:iy;
  int iz = (int)floorf(tz); iz = iz>2?2:iz;
  float fx = tx-(float)ix, fy = ty-(float)iy, fz = tz-(float)iz;
  float wxa[2] = {1.f-fx, fx};
  float wya[2] = {1.f-fy, fy};
  float wza[2] = {1.f-fz, fz};
  #pragma unroll
  for (int cc=0; cc<8; cc++){
    int cx = cc>>2, cy = (cc>>1)&1, cz = cc&1;
    gw[idx*8+cc] = w * wxa[cx]*wya[cy]*wza[cz];
    gb[idx*8+cc] = (unsigned char)((ix+cx)*16 + (iy+cy)*4 + (iz+cz));
  }
}

// ---------------- cconv0: Cin=4 -> Cout=32, 16 queries/wg ----------------
__global__ __launch_bounds__(256) void k_cconv0(const float* __restrict__ feats4, const int* __restrict__ nbrs,
    const float* __restrict__ gw, const unsigned char* __restrict__ gb,
    const float* __restrict__ W0, const float* __restrict__ b0, float* __restrict__ a0f){
  __shared__ float Bs[16*256];   // 16 q x 64 bins x 4 cin
  __shared__ float Ws[8192];     // full W0
  int t = threadIdx.x;
  int qbase = blockIdx.x*16;
  #pragma unroll
  for (int i=0;i<16;i++) Bs[i*256+t]=0.f;
  #pragma unroll
  for (int i=0;i<32;i++) Ws[i*256+t]=W0[i*256+t];
  __syncthreads();
  {
    int c = t&3, sub = t>>2;
    int q = sub>>2, k0 = (sub&3)*8;
    for (int i=0;i<8;i++){
      int idx = (qbase+q)*KN + k0 + i;
      int nbr = nbrs[idx];
      float f = feats4[nbr*4+c];
      #pragma unroll
      for (int cc=0;cc<8;cc++){
        float wgt = gw[idx*8+cc];
        if (wgt != 0.f){
          int bin = gb[idx*8+cc];
          atomicAdd(&Bs[q*256 + bin*4 + c], wgt*f);
        }
      }
    }
  }
  __syncthreads();
  int co = t&31, qq = t>>5;
  for (int qi=0;qi<2;qi++){
    int q = qq*2+qi;
    float acc = b0[co];
    #pragma unroll 8
    for (int kk=0;kk<256;kk++) acc += Bs[q*256+kk]*Ws[kk*32+co];
    a0f[(qbase+q)*32+co] = acc;
  }
}

// ---------------- LN(a0f) twice + Q1,K1,V1 (selfW) and Q2 (srcW) ----------------
__global__ __launch_bounds__(128) void k_lnproj1(const float* __restrict__ a0f,
    const float* __restrict__ lna, const float* __restrict__ lnb,
    const float* __restrict__ selfW, const float* __restrict__ selfb,
    const float* __restrict__ srcW, const float* __restrict__ srcb,
    float* __restrict__ Q1, float* __restrict__ K1o, float* __restrict__ V1, float* __restrict__ Q2){
  __shared__ float sh[4][2][32];
  int t=threadIdx.x, rr=t>>5, c=t&31;
  int r = blockIdx.x*4+rr;
  float x = a0f[r*32+c];
  float s = x;
  for (int o=16;o;o>>=1) s += __shfl_xor(s,o,32);
  float mu = s*(1.f/32.f);
  float d = x-mu;
  float s2 = d*d;
  for (int o=16;o;o>>=1) s2 += __shfl_xor(s2,o,32);
  float istd = 1.f/(sqrtf(s2*(1.f/31.f))+1e-6f);
  sh[rr][0][c] = lna[c]*d*istd + lnb[c];
  sh[rr][1][c] = lna[32+c]*d*istd + lnb[32+c];
  __syncthreads();
  float aq = selfb[c], ak = selfb[32+c], av = selfb[64+c], aq2 = srcb[c];
  for (int cc=0;cc<32;cc++){
    float v0 = sh[rr][0][cc], v1 = sh[rr][1][cc];
    aq  += v0*selfW[cc*32+c];
    ak  += v0*selfW[1024+cc*32+c];
    av  += v0*selfW[2048+cc*32+c];
    aq2 += v1*srcW[cc*32+c];
  }
  Q1[r*32+c]=aq; K1o[r*32+c]=ak; V1[r*32+c]=av; Q2[r*32+c]=aq2;
}

// ---------------- attention partials: 64 queries x 512 keys per 1-wave block ----------------
__global__ __launch_bounds__(64) void k_attn_part(const float* __restrict__ Q, const float* __restrict__ Km,
    const float* __restrict__ Vm, float* __restrict__ Pacc, float* __restrict__ Pml){
  __shared__ float Ks[32*32];
  __shared__ float Vs[32*32];
  int lane = threadIdx.x;
  int qb = blockIdx.x, kp = blockIdx.y;
  int q = qb*64 + lane;
  float qr[32];
  #pragma unroll
  for (int d=0; d<8; d++){
    float4 v = *(const float4*)(Q + q*32 + d*4);
    qr[d*4+0]=v.x; qr[d*4+1]=v.y; qr[d*4+2]=v.z; qr[d*4+3]=v.w;
  }
  float m = -1e30f, l = 0.f;
  float acc[32];
  #pragma unroll
  for (int d=0;d<32;d++) acc[d]=0.f;
  int row = lane>>1, colb = (lane&1)*16;
  for (int ch=0; ch<16; ch++){
    int kb = kp*512 + ch*32;
    #pragma unroll
    for (int i=0;i<4;i++){
      *(float4*)&Ks[row*32+colb+i*4] = *(const float4*)(Km + (kb+row)*32 + colb + i*4);
      *(float4*)&Vs[row*32+colb+i*4] = *(const float4*)(Vm + (kb+row)*32 + colb + i*4);
    }
    __syncthreads();
    float s[32];
    #pragma unroll
    for (int j=0;j<32;j++){
      float sv = 0.f;
      #pragma unroll
      for (int d=0;d<32;d++) sv += qr[d]*Ks[j*32+d];
      s[j] = sv * 0.17677669529663687f;   // 1/sqrt(32)
    }
    float cm = s[0];
    #pragma unroll
    for (int j=1;j<32;j++) cm = fmaxf(cm, s[j]);
    float mn = fmaxf(m, cm);
    float corr = expf(m - mn);
    l *= corr;
    #pragma unroll
    for (int d=0;d<32;d++) acc[d] *= corr;
    #pragma unroll
    for (int j=0;j<32;j++){
      float p = expf(s[j]-mn);
      l += p;
      #pragma unroll
      for (int d=0;d<32;d++) acc[d] += p*Vs[j*32+d];
    }
    m = mn;
    __syncthreads();
  }
  int pi = q*16 + kp;
  Pml[pi*2+0]=m; Pml[pi*2+1]=l;
  #pragma unroll
  for (int d=0;d<8;d++){
    float4 v; v.x=acc[d*4]; v.y=acc[d*4+1]; v.z=acc[d*4+2]; v.w=acc[d*4+3];
    *(float4*)(Pacc + pi*32 + d*4) = v;
  }
}

// ---------------- merge partials + out-proj + residual(a0f) ----------------
__global__ __launch_bounds__(128) void k_merge(const float* __restrict__ Pacc, const float* __restrict__ Pml,
    const float* __restrict__ resid, const float* __restrict__ Wo, const float* __restrict__ bo,
    float* __restrict__ outp){
  __shared__ float sh[4][32];
  int t=threadIdx.x, rr=t>>5, c=t&31;
  int r = blockIdx.x*4+rr;
  float m = -1e30f;
  for (int p=0;p<16;p++) m = fmaxf(m, Pml[(r*16+p)*2]);
  float l = 0.f, a = 0.f;
  for (int p=0;p<16;p++){
    float mp = Pml[(r*16+p)*2], lp = Pml[(r*16+p)*2+1];
    float sc = expf(mp-m);
    l += lp*sc;
    a += Pacc[(r*16+p)*32+c]*sc;
  }
  sh[rr][c] = a/l;
  __syncthreads();
  float acc = bo[c];
  for (int cc=0;cc<32;cc++) acc += sh[rr][cc]*Wo[cc*32+c];
  outp[r*32+c] = resid[r*32+c] + acc;
}

// ---------------- K2,V2 = h1 @ srcW[1],srcW[2] ----------------
__global__ __launch_bounds__(128) void k_projkv(const float* __restrict__ h1,
    const float* __restrict__ srcW, const float* __restrict__ srcb,
    float* __restrict__ K2, float* __restrict__ V2){
  __shared__ float sh[4][32];
  int t=threadIdx.x, rr=t>>5, c=t&31;
  int r = blockIdx.x*4+rr;
  sh[rr][c] = h1[r*32+c];
  __syncthreads();
  float ak = srcb[32+c], av = srcb[64+c];
  for (int cc=0;cc<32;cc++){
    float v = sh[rr][cc];
    ak += v*srcW[1024+cc*32+c];
    av += v*srcW[2048+cc*32+c];
  }
  K2[r*32+c]=ak; V2[r*32+c]=av;
}

// ---------------- LN(h2) + FFN 32->64->64 ----------------
__global__ __launch_bounds__(128) void k_lnffn(const float* __restrict__ h2,
    const float* __restrict__ lna, const float* __restrict__ lnb,
    const float* __restrict__ w1, const float* __restrict__ b1,
    const float* __restrict__ w2, const float* __restrict__ b2, float* __restrict__ x0){
  __shared__ float sh[4][32];
  __shared__ float sh2[4][64];
  int t=threadIdx.x, rr=t>>5, c=t&31;
  int r = blockIdx.x*4+rr;
  float x = h2[r*32+c];
  float s = x;
  for (int o=16;o;o>>=1) s += __shfl_xor(s,o,32);
  float mu = s*(1.f/32.f);
  float d = x-mu;
  float s2 = d*d;
  for (int o=16;o;o>>=1) s2 += __shfl_xor(s2,o,32);
  float istd = 1.f/(sqrtf(s2*(1.f/31.f))+1e-6f);
  sh[rr][c] = lna[64+c]*d*istd + lnb[64+c];
  __syncthreads();
  #pragma unroll
  for (int jj=0;jj<2;jj++){
    int j = c + jj*32;
    float h = b1[j];
    for (int cc=0;cc<32;cc++) h += sh[rr][cc]*w1[cc*64+j];
    sh2[rr][j] = fmaxf(h, 0.f);
  }
  __syncthreads();
  #pragma unroll
  for (int jj=0;jj<2;jj++){
    int j = c + jj*32;
    float o = b2[j];
    for (int kk=0;kk<64;kk++) o += sh2[rr][kk]*w2[kk*64+j];
    x0[r*64+j] = o;
  }
}

// ---------------- big cconv layer v3: barrier-free GEMM, no spill ----------------
// LDS: Bs 32768 f32 (128 KB) | Yb2 4096 f32 (16 KB, 8 kp-group slabs)
__global__ __launch_bounds__(512, 2) void k_cconvbig(const float* __restrict__ xin, const int* __restrict__ nbrs,
    const float* __restrict__ gw, const unsigned char* __restrict__ gb,
    const float* __restrict__ W, const float* __restrict__ cb,
    const float* __restrict__ dw, const float* __restrict__ db, float* __restrict__ xout){
  extern __shared__ float smem[];
  float* Bs  = smem;           // 8 q x 4096 k
  float* Yb2 = smem + 32768;   // 8 groups x 512
  int t = threadIdx.x;
  int lane = t & 63, w = t >> 6;
  int qbase = blockIdx.x*8;
  #pragma unroll
  for (int i=0;i<16;i++) ((float4*)Bs)[i*512+t] = make_float4(0.f,0.f,0.f,0.f);
  ((float4*)Yb2)[t]     = make_float4(0.f,0.f,0.f,0.f);
  ((float4*)Yb2)[512+t] = make_float4(0.f,0.f,0.f,0.f);
  __syncthreads();
  // ---- scatter: wave w -> query qbase+w, lane = ci; 2-deep pipeline ----
  {
    int n = qbase + w;
    const float4* gw4 = (const float4*)(gw + (size_t)n*KN*8);
    const uint2*  gb2 = (const uint2*)(gb + (size_t)n*KN*8);
    const int* nb = nbrs + n*KN;
    float4 g0 = gw4[0], g1 = gw4[1];
    uint2  gv = gb2[0];
    int nbr1 = nb[1];
    float xv = fmaxf(xin[(size_t)nb[0]*64 + lane], 0.f);
    for (int k=0;k<KN;k++){
      float4 cg0=g0, cg1=g1; uint2 cgv=gv; float cxv=xv;
      int nbrn = nbr1;
      if (k<KN-1){
        g0 = gw4[(k+1)*2]; g1 = gw4[(k+1)*2+1]; gv = gb2[k+1];
        xv = fmaxf(xin[(size_t)nbrn*64 + lane], 0.f);
        if (k<KN-2) nbr1 = nb[k+2];
      }
      float wsum = cg0.x+cg0.y+cg0.z+cg0.w+cg1.x+cg1.y+cg1.z+cg1.w;
      if (wsum > 0.f){
        unsigned bx = cgv.x, by = cgv.y;
        float* Bw = Bs + w*4096 + lane;
        atomicAdd(Bw + (int)( bx      &255u)*64, cg0.x*cxv);
        atomicAdd(Bw + (int)((bx>> 8) &255u)*64, cg0.y*cxv);
        atomicAdd(Bw + (int)((bx>>16) &255u)*64, cg0.z*cxv);
        atomicAdd(Bw + (int)( bx>>24       )*64, cg0.w*cxv);
        atomicAdd(Bw + (int)( by      &255u)*64, cg1.x*cxv);
        atomicAdd(Bw + (int)((by>> 8) &255u)*64, cg1.y*cxv);
        atomicAdd(Bw + (int)((by>>16) &255u)*64, cg1.z*cxv);
        atomicAdd(Bw + (int)( by>>24       )*64, cg1.w*cxv);
      }
    }
  }
  __syncthreads();
  // ---- GEMM: thread = (cot = t&7 -> 8 co, kp = t>>3 -> 4k per 256-k window); no barriers ----
  {
    int cot = t&7, kp = t>>3;
    int co0 = cot*8;
    float acc[8][8];
    #pragma unroll
    for (int q=0;q<8;q++)
      #pragma unroll
      for (int j=0;j<8;j++) acc[q][j]=0.f;
    for (int win=0; win<16; ++win){
      int k0 = win*256 + kp*4;
      float4 bf[8];
      #pragma unroll
      for (int q=0;q<8;q++) bf[q] = *(const float4*)&Bs[q*4096 + k0];
      float4 wf[4][2];
      #pragma unroll
      for (int j=0;j<4;j++){
        const float* wp = W + (size_t)(k0+j)*64 + co0;
        wf[j][0] = *(const float4*)wp;
        wf[j][1] = *(const float4*)(wp+4);
      }
      #pragma unroll
      for (int q=0;q<8;q++){
        #pragma unroll
        for (int j=0;j<4;j++){
          float bb = (j==0)?bf[q].x:((j==1)?bf[q].y:((j==2)?bf[q].z:bf[q].w));
          acc[q][0] += bb*wf[j][0].x;
          acc[q][1] += bb*wf[j][0].y;
          acc[q][2] += bb*wf[j][0].z;
          acc[q][3] += bb*wf[j][0].w;
          acc[q][4] += bb*wf[j][1].x;
          acc[q][5] += bb*wf[j][1].y;
          acc[q][6] += bb*wf[j][1].z;
          acc[q][7] += bb*wf[j][1].w;
        }
      }
    }
    // reduce into per-kp-group slabs: all 64 addrs distinct per instr
    int g = kp & 7;
    #pragma unroll
    for (int q=0;q<8;q++)
      #pragma unroll
      for (int j=0;j<8;j++)
        atomicAdd(&Yb2[g*512 + q*64 + co0 + j], acc[q][j]);
  }
  __syncthreads();
  // ---- epilogue: sum slabs + bias + dense + residual ----
  {
    int q = t>>6, co = t&63;
    int n = qbase + q;
    float y = cb[co] + db[co];
    #pragma unroll
    for (int g=0; g<8; g++) y += Yb2[g*512 + q*64 + co];
    const float* xr = xin + (size_t)n*64;
    for (int ci=0; ci<64; ci++) y += fmaxf(xr[ci], 0.f) * dw[ci*64+co];
    xout[(size_t)n*64+co] = y + xr[co];
  }
}

// ---------------- final cconv layer v3: wave=q, lane=k, butterfly reduce ----------------
__global__ __launch_bounds__(512, 2) void k_cconvfinal(const float* __restrict__ xin, const int* __restrict__ nbrs,
    const float* __restrict__ gw, const unsigned char* __restrict__ gb,
    const float* __restrict__ W3, const float* __restrict__ cb3,
    const float* __restrict__ dw3, const float* __restrict__ db3,
    const float* __restrict__ pos, const float* __restrict__ pos2, float* __restrict__ outp){
  extern __shared__ float smem[];
  float* Bs = smem;            // 8 x 4096
  float* Yf = smem + 32768;    // 24 floats
  int t = threadIdx.x;
  int lane = t & 63, w = t >> 6;
  int qbase = blockIdx.x*8;
  #pragma unroll
  for (int i=0;i<16;i++) ((float4*)Bs)[i*512+t] = make_float4(0.f,0.f,0.f,0.f);
  if (t < 24) Yf[t] = 0.f;
  __syncthreads();
  // scatter (same pipeline as big)
  {
    int n = qbase + w;
    const float4* gw4 = (const float4*)(gw + (size_t)n*KN*8);
    const uint2*  gb2 = (const uint2*)(gb + (size_t)n*KN*8);
    const int* nb = nbrs + n*KN;
    float4 g0 = gw4[0], g1 = gw4[1];
    uint2  gv = gb2[0];
    int nbr1 = nb[1];
    float xv = fmaxf(xin[(size_t)nb[0]*64 + lane], 0.f);
    for (int k=0;k<KN;k++){
      float4 cg0=g0, cg1=g1; uint2 cgv=gv; float cxv=xv;
      int nbrn = nbr1;
      if (k<KN-1){
        g0 = gw4[(k+1)*2]; g1 = gw4[(k+1)*2+1]; gv = gb2[k+1];
        xv = fmaxf(xin[(size_t)nbrn*64 + lane], 0.f);
        if (k<KN-2) nbr1 = nb[k+2];
      }
      float wsum = cg0.x+cg0.y+cg0.z+cg0.w+cg1.x+cg1.y+cg1.z+cg1.w;
      if (wsum > 0.f){
        unsigned bx = cgv.x, by = cgv.y;
        float* Bw = Bs + w*4096 + lane;
        atomicAdd(Bw + (int)( bx      &255u)*64, cg0.x*cxv);
        atomicAdd(Bw + (int)((bx>> 8) &255u)*64, cg0.y*cxv);
        atomicAdd(Bw + (int)((bx>>16) &255u)*64, cg0.z*cxv);
        atomicAdd(Bw + (int)( bx>>24       )*64, cg0.w*cxv);
        atomicAdd(Bw + (int)( by      &255u)*64, cg1.x*cxv);
        atomicAdd(Bw + (int)((by>> 8) &255u)*64, cg1.y*cxv);
        atomicAdd(Bw + (int)((by>>16) &255u)*64, cg1.z*cxv);
        atomicAdd(Bw + (int)( by>>24       )*64, cg1.w*cxv);
      }
    }
  }
  __syncthreads();
  // GEMM: wave w -> q=w, lane covers 4k-quads; coalesced B (LDS) + W3 (global)
  {
    float a0=0.f, a1=0.f, a2=0.f;
    #pragma unroll 4
    for (int i=0;i<16;i++){
      int k = i*256 + lane*4;
      float4 b = *(const float4*)&Bs[w*4096 + k];
      const float* wp = W3 + (size_t)k*3;
      float4 wa = *(const float4*)wp;
      float4 wb = *(const float4*)(wp+4);
      float4 wc = *(const float4*)(wp+8);
      a0 += b.x*wa.x + b.y*wa.w + b.z*wb.z + b.w*wc.y;
      a1 += b.x*wa.y + b.y*wb.x + b.z*wb.w + b.w*wc.z;
      a2 += b.x*wa.z + b.y*wb.y + b.z*wc.x + b.w*wc.w;
    }
    #pragma unroll
    for (int m=1; m<64; m<<=1){
      a0 += __shfl_xor(a0, m);
      a1 += __shfl_xor(a1, m);
      a2 += __shfl_xor(a2, m);
    }
    if (lane == 0){
      Yf[w*3+0] = a0; Yf[w*3+1] = a1; Yf[w*3+2] = a2;
    }
  }
  __syncthreads();
  if (t < 24){
    int q = t/3, co = t%3;
    int n = qbase + q;
    float y = Yf[t] + cb3[co] + db3[co];
    for (int cc=0; cc<64; cc++) y += fmaxf(xin[(size_t)n*64+cc],0.f)*dw3[cc*3+co];
    float pc = y*(1.f/128.f);
    float po = pos2[n*3+co] + pc;
    outp[n*3+co] = po;
    outp[NP*3 + n*3+co] = (po - pos[n*3+co]) / 0.02f;
  }
}

extern "C" void kernel_launch(void* const* d_in, const int* in_sizes, int n_in,
                              void* d_out, int out_size, void* d_ws, size_t ws_size,
                              hipStream_t stream) {
  const float* pos   = (const float*)d_in[0];
  const float* vel   = (const float*)d_in[1];
  const int*   fn    = (const int*)d_in[4];
  const float* cw0f  = (const float*)d_in[6];
  const float* cb0f  = (const float*)d_in[7];
  const float* cw1   = (const float*)d_in[10];
  const float* cb1   = (const float*)d_in[11];
  const float* cw2   = (const float*)d_in[12];
  const float* cb2   = (const float*)d_in[13];
  const float* cw3   = (const float*)d_in[14];
  const float* cb3   = (const float*)d_in[15];
  const float* dw1   = (const float*)d_in[16];
  const float* db1   = (const float*)d_in[17];
  const float* dw2   = (const float*)d_in[18];
  const float* db2   = (const float*)d_in[19];
  const float* dw3   = (const float*)d_in[20];
  const float* db3   = (const float*)d_in[21];
  const float* selfW = (const float*)d_in[22];
  const float* selfb = (const float*)d_in[23];
  const float* srcW  = (const float*)d_in[24];
  const float* srcb  = (const float*)d_in[25];
  const float* lna   = (const float*)d_in[26];
  const float* lnb   = (const float*)d_in[27];
  const float* ffw1  = (const float*)d_in[28];
  const float* ffb1  = (const float*)d_in[29];
  const float* ffw2  = (const float*)d_in[30];
  const float* ffb2  = (const float*)d_in[31];

  float* ws = (float*)d_ws;
  float* pos2   = ws + 0;          // 24576
  float* feats4 = ws + 24576;      // 32768
  float* a0f    = ws + 57344;      // 262144
  float* Q1     = ws + 319488;     // 262144
  float* K1     = ws + 581632;     // 262144
  float* V1     = ws + 843776;     // 262144
  float* Q2     = ws + 1105920;    // 262144
  float* h1     = ws + 1368064;    // 262144
  float* K2     = ws + 1630208;    // 262144
  float* V2     = ws + 1892352;    // 262144
  float* h2     = ws + 2154496;    // 262144
  float* Pacc   = ws + 2416640;    // 4194304
  float* Pml    = ws + 6610944;    // 262144
  float* x0     = ws + 6873088;    // 524288
  float* x1     = ws + 7397376;    // 524288
  float* x2     = ws + 7921664;    // 524288 -> ends 8445952
  float* gw     = ws + 8445952;    // 2097152 -> ends 10543104
  unsigned char* gb = (unsigned char*)(ws + 10543104);  // 2 MB

  float* outp = (float*)d_out;

  hipFuncSetAttribute(reinterpret_cast<const void*>(k_cconvbig),
                      hipFuncAttributeMaxDynamicSharedMemorySize, 147456);
  hipFuncSetAttribute(reinterpret_cast<const void*>(k_cconvfinal),
                      hipFuncAttributeMaxDynamicSharedMemorySize, 131200);

  k_prep<<<NP/256, 256, 0, stream>>>(pos, vel, pos2, feats4);
  k_geom<<<NP*KN/256, 256, 0, stream>>>(pos2, fn, gw, gb);
  k_cconv0<<<NP/16, 256, 0, stream>>>(feats4, fn, gw, gb, cw0f, cb0f, a0f);
  k_lnproj1<<<NP/4, 128, 0, stream>>>(a0f, lna, lnb, selfW, selfb, srcW, srcb, Q1, K1, V1, Q2);
  k_attn_part<<<dim3(NP/64, 16), 64, 0, stream>>>(Q1, K1, V1, Pacc, Pml);
  k_merge<<<NP/4, 128, 0, stream>>>(Pacc, Pml, a0f, selfW+3072, selfb+96, h1);
  k_projkv<<<NP/4, 128, 0, stream>>>(h1, srcW, srcb, K2, V2);
  k_attn_part<<<dim3(NP/64, 16), 64, 0, stream>>>(Q2, K2, V2, Pacc, Pml);
  k_merge<<<NP/4, 128, 0, stream>>>(Pacc, Pml, a0f, srcW+3072, srcb+96, h2);
  k_lnffn<<<NP/4, 128, 0, stream>>>(h2, lna, lnb, ffw1, ffb1, ffw2, ffb2, x0);
  k_cconvbig<<<NP/8, 512, 147456, stream>>>(x0, fn, gw, gb, cw1, cb1, dw1, db1, x1);
  k_cconvbig<<<NP/8, 512, 147456, stream>>>(x1, fn, gw, gb, cw2, cb2, dw2, db2, x2);
  k_cconvfinal<<<NP/8, 512, 131200, stream>>>(x2, fn, gw, gb, cw3, cb3, dw3, db3, pos, pos2, outp);
}

// Round 4
// 1831.000 us; speedup vs baseline: 1.2353x; 1.1179x over previous
//
#include <hip/hip_runtime.h>
#include <math.h>

#define NP 8192
#define KN 32

__device__ __forceinline__ float sgnf(float x){ return (x>0.f)?1.f:((x<0.f)?-1.f:0.f); }

// ---------------- prep: pos2, vel2, feats4 ----------------
__global__ __launch_bounds__(256) void k_prep(const float* __restrict__ pos, const float* __restrict__ vel,
                                              float* __restrict__ pos2, float* __restrict__ feats4){
  int i = blockIdx.x*256 + threadIdx.x;
  const float DT = 0.02f;
  float vx = vel[i*3+0], vy = vel[i*3+1], vz = vel[i*3+2];
  float v2x = vx;
  float v2y = vy + DT*(-9.81f);
  float v2z = vz;
  float px = pos[i*3+0] + (DT*(v2x+vx))*0.5f;
  float py = pos[i*3+1] + (DT*(v2y+vy))*0.5f;
  float pz = pos[i*3+2] + (DT*(v2z+vz))*0.5f;
  pos2[i*3+0]=px; pos2[i*3+1]=py; pos2[i*3+2]=pz;
  feats4[i*4+0]=1.f; feats4[i*4+1]=v2x; feats4[i*4+2]=v2y; feats4[i*4+3]=v2z;
}

// ---------------- geometry: per (n,k) 8 corner weights + bins ----------------
__global__ __launch_bounds__(256) void k_geom(const float* __restrict__ pos2, const int* __restrict__ nbrs,
                                              float* __restrict__ gw, unsigned char* __restrict__ gb){
  int idx = blockIdx.x*256 + threadIdx.x;   // < NP*KN
  int n = idx >> 5;
  int nbr = nbrs[idx];
  const float R = 0.5f * (float)(1.5*6.0*0.025);
  float x = (pos2[nbr*3+0]-pos2[n*3+0])/R;
  float y = (pos2[nbr*3+1]-pos2[n*3+1])/R;
  float z = (pos2[nbr*3+2]-pos2[n*3+2])/R;
  float sq = x*x+y*y+z*z;
  float w = 0.f;
  if (sq < 1.f){ float t1 = 1.f-sq; w = t1*t1*t1; }
  if (nbr == n) w = 0.f;     // exclude_self
  const float eps = 1e-8f;
  float norm = sqrtf(sq);
  float sq_xy = x*x+y*y;
  bool polar = 1.25f*z*z > sq_xy;
  float sa = sqrtf(3.f*norm/(norm+fabsf(z)+eps));
  float sb = norm/(sqrtf(sq_xy)+eps);
  float xc = polar ? x*sa : x*sb;
  float yc = polar ? y*sa : y*sb;
  float zc = polar ? sgnf(z)*norm : 1.5f*z;
  if (sq < eps){ xc=x; yc=y; zc=z; }
  float nxy = sqrtf(xc*xc+yc*yc);
  const float fo_pi = (float)(4.0/3.141592653589793);
  float sx = (fabsf(xc)>eps) ? xc : eps;
  float sy = (fabsf(yc)>eps) ? yc : eps;
  float ux = sgnf(xc)*nxy;
  float vv = sgnf(yc)*nxy;
  bool xbig = fabsf(yc) <= fabsf(xc);
  float u = xbig ? ux : vv*fo_pi*atanf(xc/sy);
  float v = xbig ? ux*fo_pi*atanf(yc/sx) : vv;
  if (nxy < eps){ u = xc; v = yc; }
  float tx = fminf(fmaxf((u  + 1.f)*1.5f, 0.f), 3.f);
  float ty = fminf(fmaxf((v  + 1.f)*1.5f, 0.f), 3.f);
  float tz = fminf(fmaxf((zc + 1.f)*1.5f, 0.f), 3.f);
  int ix = (int)floorf(tx); ix = ix>2?2:ix;
  int iy = (int)floorf(ty); iy = iy>2?2:iy;
  int iz = (int)floorf(tz); iz = iz>2?2:iz;
  float fx = tx-(float)ix, fy = ty-(float)iy, fz = tz-(float)iz;
  float wxa[2] = {1.f-fx, fx};
  float wya[2] = {1.f-fy, fy};
  float wza[2] = {1.f-fz, fz};
  #pragma unroll
  for (int cc=0; cc<8; cc++){
    int cx = cc>>2, cy = (cc>>1)&1, cz = cc&1;
    gw[idx*8+cc] = w * wxa[cx]*wya[cy]*wza[cz];
    gb[idx*8+cc] = (unsigned char)((ix+cx)*16 + (iy+cy)*4 + (iz+cz));
  }
}

// ---------------- cconv0: Cin=4 -> Cout=32, 16 queries/wg ----------------
__global__ __launch_bounds__(256) void k_cconv0(const float* __restrict__ feats4, const int* __restrict__ nbrs,
    const float* __restrict__ gw, const unsigned char* __restrict__ gb,
    const float* __restrict__ W0, const float* __restrict__ b0, float* __restrict__ a0f){
  __shared__ float Bs[16*256];   // 16 q x 64 bins x 4 cin
  __shared__ float Ws[8192];     // full W0
  int t = threadIdx.x;
  int qbase = blockIdx.x*16;
  #pragma unroll
  for (int i=0;i<16;i++) Bs[i*256+t]=0.f;
  #pragma unroll
  for (int i=0;i<32;i++) Ws[i*256+t]=W0[i*256+t];
  __syncthreads();
  {
    int c = t&3, sub = t>>2;
    int q = sub>>2, k0 = (sub&3)*8;
    for (int i=0;i<8;i++){
      int idx = (qbase+q)*KN + k0 + i;
      int nbr = nbrs[idx];
      float f = feats4[nbr*4+c];
      #pragma unroll
      for (int cc=0;cc<8;cc++){
        float wgt = gw[idx*8+cc];
        if (wgt != 0.f){
          int bin = gb[idx*8+cc];
          atomicAdd(&Bs[q*256 + bin*4 + c], wgt*f);
        }
      }
    }
  }
  __syncthreads();
  int co = t&31, qq = t>>5;
  for (int qi=0;qi<2;qi++){
    int q = qq*2+qi;
    float acc = b0[co];
    #pragma unroll 8
    for (int kk=0;kk<256;kk++) acc += Bs[q*256+kk]*Ws[kk*32+co];
    a0f[(qbase+q)*32+co] = acc;
  }
}

// ---------------- LN(a0f) twice + Q1,K1,V1 (selfW) and Q2 (srcW) ----------------
__global__ __launch_bounds__(128) void k_lnproj1(const float* __restrict__ a0f,
    const float* __restrict__ lna, const float* __restrict__ lnb,
    const float* __restrict__ selfW, const float* __restrict__ selfb,
    const float* __restrict__ srcW, const float* __restrict__ srcb,
    float* __restrict__ Q1, float* __restrict__ K1o, float* __restrict__ V1, float* __restrict__ Q2){
  __shared__ float sh[4][2][32];
  int t=threadIdx.x, rr=t>>5, c=t&31;
  int r = blockIdx.x*4+rr;
  float x = a0f[r*32+c];
  float s = x;
  for (int o=16;o;o>>=1) s += __shfl_xor(s,o,32);
  float mu = s*(1.f/32.f);
  float d = x-mu;
  float s2 = d*d;
  for (int o=16;o;o>>=1) s2 += __shfl_xor(s2,o,32);
  float istd = 1.f/(sqrtf(s2*(1.f/31.f))+1e-6f);
  sh[rr][0][c] = lna[c]*d*istd + lnb[c];
  sh[rr][1][c] = lna[32+c]*d*istd + lnb[32+c];
  __syncthreads();
  float aq = selfb[c], ak = selfb[32+c], av = selfb[64+c], aq2 = srcb[c];
  for (int cc=0;cc<32;cc++){
    float v0 = sh[rr][0][cc], v1 = sh[rr][1][cc];
    aq  += v0*selfW[cc*32+c];
    ak  += v0*selfW[1024+cc*32+c];
    av  += v0*selfW[2048+cc*32+c];
    aq2 += v1*srcW[cc*32+c];
  }
  Q1[r*32+c]=aq; K1o[r*32+c]=ak; V1[r*32+c]=av; Q2[r*32+c]=aq2;
}

// ---------------- attention partials: 64 queries x 512 keys per 1-wave block ----------------
__global__ __launch_bounds__(64) void k_attn_part(const float* __restrict__ Q, const float* __restrict__ Km,
    const float* __restrict__ Vm, float* __restrict__ Pacc, float* __restrict__ Pml){
  __shared__ float Ks[32*32];
  __shared__ float Vs[32*32];
  int lane = threadIdx.x;
  int qb = blockIdx.x, kp = blockIdx.y;
  int q = qb*64 + lane;
  float qr[32];
  #pragma unroll
  for (int d=0; d<8; d++){
    float4 v = *(const float4*)(Q + q*32 + d*4);
    qr[d*4+0]=v.x; qr[d*4+1]=v.y; qr[d*4+2]=v.z; qr[d*4+3]=v.w;
  }
  float m = -1e30f, l = 0.f;
  float acc[32];
  #pragma unroll
  for (int d=0;d<32;d++) acc[d]=0.f;
  int row = lane>>1, colb = (lane&1)*16;
  for (int ch=0; ch<16; ch++){
    int kb = kp*512 + ch*32;
    #pragma unroll
    for (int i=0;i<4;i++){
      *(float4*)&Ks[row*32+colb+i*4] = *(const float4*)(Km + (kb+row)*32 + colb + i*4);
      *(float4*)&Vs[row*32+colb+i*4] = *(const float4*)(Vm + (kb+row)*32 + colb + i*4);
    }
    __syncthreads();
    float s[32];
    #pragma unroll
    for (int j=0;j<32;j++){
      float sv = 0.f;
      #pragma unroll
      for (int d=0;d<32;d++) sv += qr[d]*Ks[j*32+d];
      s[j] = sv * 0.17677669529663687f;   // 1/sqrt(32)
    }
    float cm = s[0];
    #pragma unroll
    for (int j=1;j<32;j++) cm = fmaxf(cm, s[j]);
    float mn = fmaxf(m, cm);
    float corr = expf(m - mn);
    l *= corr;
    #pragma unroll
    for (int d=0;d<32;d++) acc[d] *= corr;
    #pragma unroll
    for (int j=0;j<32;j++){
      float p = expf(s[j]-mn);
      l += p;
      #pragma unroll
      for (int d=0;d<32;d++) acc[d] += p*Vs[j*32+d];
    }
    m = mn;
    __syncthreads();
  }
  int pi = q*16 + kp;
  Pml[pi*2+0]=m; Pml[pi*2+1]=l;
  #pragma unroll
  for (int d=0;d<8;d++){
    float4 v; v.x=acc[d*4]; v.y=acc[d*4+1]; v.z=acc[d*4+2]; v.w=acc[d*4+3];
    *(float4*)(Pacc + pi*32 + d*4) = v;
  }
}

// ---------------- merge partials + out-proj + residual(a0f) ----------------
__global__ __launch_bounds__(128) void k_merge(const float* __restrict__ Pacc, const float* __restrict__ Pml,
    const float* __restrict__ resid, const float* __restrict__ Wo, const float* __restrict__ bo,
    float* __restrict__ outp){
  __shared__ float sh[4][32];
  int t=threadIdx.x, rr=t>>5, c=t&31;
  int r = blockIdx.x*4+rr;
  float m = -1e30f;
  for (int p=0;p<16;p++) m = fmaxf(m, Pml[(r*16+p)*2]);
  float l = 0.f, a = 0.f;
  for (int p=0;p<16;p++){
    float mp = Pml[(r*16+p)*2], lp = Pml[(r*16+p)*2+1];
    float sc = expf(mp-m);
    l += lp*sc;
    a += Pacc[(r*16+p)*32+c]*sc;
  }
  sh[rr][c] = a/l;
  __syncthreads();
  float acc = bo[c];
  for (int cc=0;cc<32;cc++) acc += sh[rr][cc]*Wo[cc*32+c];
  outp[r*32+c] = resid[r*32+c] + acc;
}

// ---------------- K2,V2 = h1 @ srcW[1],srcW[2] ----------------
__global__ __launch_bounds__(128) void k_projkv(const float* __restrict__ h1,
    const float* __restrict__ srcW, const float* __restrict__ srcb,
    float* __restrict__ K2, float* __restrict__ V2){
  __shared__ float sh[4][32];
  int t=threadIdx.x, rr=t>>5, c=t&31;
  int r = blockIdx.x*4+rr;
  sh[rr][c] = h1[r*32+c];
  __syncthreads();
  float ak = srcb[32+c], av = srcb[64+c];
  for (int cc=0;cc<32;cc++){
    float v = sh[rr][cc];
    ak += v*srcW[1024+cc*32+c];
    av += v*srcW[2048+cc*32+c];
  }
  K2[r*32+c]=ak; V2[r*32+c]=av;
}

// ---------------- LN(h2) + FFN 32->64->64 ----------------
__global__ __launch_bounds__(128) void k_lnffn(const float* __restrict__ h2,
    const float* __restrict__ lna, const float* __restrict__ lnb,
    const float* __restrict__ w1, const float* __restrict__ b1,
    const float* __restrict__ w2, const float* __restrict__ b2, float* __restrict__ x0){
  __shared__ float sh[4][32];
  __shared__ float sh2[4][64];
  int t=threadIdx.x, rr=t>>5, c=t&31;
  int r = blockIdx.x*4+rr;
  float x = h2[r*32+c];
  float s = x;
  for (int o=16;o;o>>=1) s += __shfl_xor(s,o,32);
  float mu = s*(1.f/32.f);
  float d = x-mu;
  float s2 = d*d;
  for (int o=16;o;o>>=1) s2 += __shfl_xor(s2,o,32);
  float istd = 1.f/(sqrtf(s2*(1.f/31.f))+1e-6f);
  sh[rr][c] = lna[64+c]*d*istd + lnb[64+c];
  __syncthreads();
  #pragma unroll
  for (int jj=0;jj<2;jj++){
    int j = c + jj*32;
    float h = b1[j];
    for (int cc=0;cc<32;cc++) h += sh[rr][cc]*w1[cc*64+j];
    sh2[rr][j] = fmaxf(h, 0.f);
  }
  __syncthreads();
  #pragma unroll
  for (int jj=0;jj<2;jj++){
    int j = c + jj*32;
    float o = b2[j];
    for (int kk=0;kk<64;kk++) o += sh2[rr][kk]*w2[kk*64+j];
    x0[r*64+j] = o;
  }
}

// ---------------- big cconv layer v4: small reg tile (no spill), barrier-free GEMM ----------------
// lane = cog(16)*4co x qg(4)*{q,q+4}; wave w = k-slice [w*512,(w+1)*512)
// LDS: Bs 32768 f32 (swizzled: q*4096 + (k ^ q*8)) | Yw 8 slabs x 512 f32
__global__ __launch_bounds__(512) void k_cconvbig(const float* __restrict__ xin, const int* __restrict__ nbrs,
    const float* __restrict__ gw, const unsigned char* __restrict__ gb,
    const float* __restrict__ W, const float* __restrict__ cb,
    const float* __restrict__ dw, const float* __restrict__ db, float* __restrict__ xout){
  extern __shared__ float smem[];
  float* Bs = smem;           // 8 q x 4096 k (swizzled)
  float* Yw = smem + 32768;   // 8 waves x 512
  int t = threadIdx.x;
  int lane = t & 63, w = t >> 6;
  int qbase = blockIdx.x*8;
  #pragma unroll
  for (int i=0;i<18;i++) ((float4*)smem)[i*512+t] = make_float4(0.f,0.f,0.f,0.f);
  __syncthreads();
  // ---- scatter: wave w -> query qbase+w, lane = ci; swizzled lane base ----
  {
    int n = qbase + w;
    const float4* gw4 = (const float4*)(gw + (size_t)n*KN*8);
    const uint2*  gb2 = (const uint2*)(gb + (size_t)n*KN*8);
    const int* nb = nbrs + n*KN;
    float4 g0 = gw4[0], g1 = gw4[1];
    uint2  gv = gb2[0];
    int nbr1 = nb[1];
    float xv = fmaxf(xin[(size_t)nb[0]*64 + lane], 0.f);
    float* Bw = Bs + w*4096 + (lane ^ (w*8));   // swizzle: lane-constant XOR
    for (int k=0;k<KN;k++){
      float4 cg0=g0, cg1=g1; uint2 cgv=gv; float cxv=xv;
      int nbrn = nbr1;
      if (k<KN-1){
        g0 = gw4[(k+1)*2]; g1 = gw4[(k+1)*2+1]; gv = gb2[k+1];
        xv = fmaxf(xin[(size_t)nbrn*64 + lane], 0.f);
        if (k<KN-2) nbr1 = nb[k+2];
      }
      float wsum = cg0.x+cg0.y+cg0.z+cg0.w+cg1.x+cg1.y+cg1.z+cg1.w;
      if (wsum > 0.f){
        unsigned bx = cgv.x, by = cgv.y;
        atomicAdd(Bw + (int)( bx      &255u)*64, cg0.x*cxv);
        atomicAdd(Bw + (int)((bx>> 8) &255u)*64, cg0.y*cxv);
        atomicAdd(Bw + (int)((bx>>16) &255u)*64, cg0.z*cxv);
        atomicAdd(Bw + (int)( bx>>24       )*64, cg0.w*cxv);
        atomicAdd(Bw + (int)( by      &255u)*64, cg1.x*cxv);
        atomicAdd(Bw + (int)((by>> 8) &255u)*64, cg1.y*cxv);
        atomicAdd(Bw + (int)((by>>16) &255u)*64, cg1.z*cxv);
        atomicAdd(Bw + (int)( by>>24       )*64, cg1.w*cxv);
      }
    }
  }
  __syncthreads();
  // ---- GEMM: thread = (cog: 4 co, qg: q & q+4), wave = 512-k slice; W from L2 (broadcast) ----
  {
    int cog = lane & 15, qg = lane >> 4;
    int co0 = cog*4;
    int q0 = qg, q1 = qg + 4;
    const float* B0 = Bs + q0*4096;
    const float* B1 = Bs + q1*4096;
    int s0 = q0*8, s1 = q1*8;
    float a00=0.f,a01=0.f,a02=0.f,a03=0.f;
    float a10=0.f,a11=0.f,a12=0.f,a13=0.f;
    int kbase = w*512;
    #pragma unroll 2
    for (int c=0; c<128; ++c){
      int k0 = kbase + c*4;
      float4 b0 = *(const float4*)&B0[k0 ^ s0];
      float4 b1 = *(const float4*)&B1[k0 ^ s1];
      const float* wp = W + (size_t)k0*64 + co0;
      float4 w0 = *(const float4*)(wp);
      float4 w1 = *(const float4*)(wp + 64);
      float4 w2 = *(const float4*)(wp + 128);
      float4 w3 = *(const float4*)(wp + 192);
      a00 += b0.x*w0.x + b0.y*w1.x + b0.z*w2.x + b0.w*w3.x;
      a01 += b0.x*w0.y + b0.y*w1.y + b0.z*w2.y + b0.w*w3.y;
      a02 += b0.x*w0.z + b0.y*w1.z + b0.z*w2.z + b0.w*w3.z;
      a03 += b0.x*w0.w + b0.y*w1.w + b0.z*w2.w + b0.w*w3.w;
      a10 += b1.x*w0.x + b1.y*w1.x + b1.z*w2.x + b1.w*w3.x;
      a11 += b1.x*w0.y + b1.y*w1.y + b1.z*w2.y + b1.w*w3.y;
      a12 += b1.x*w0.z + b1.y*w1.z + b1.z*w2.z + b1.w*w3.z;
      a13 += b1.x*w0.w + b1.y*w1.w + b1.z*w2.w + b1.w*w3.w;
    }
    // per-wave slab: each lane owns (q0,q1) x co0..co0+3 -> no collisions
    float* Y = Yw + w*512;
    Y[q0*64+co0+0]=a00; Y[q0*64+co0+1]=a01; Y[q0*64+co0+2]=a02; Y[q0*64+co0+3]=a03;
    Y[q1*64+co0+0]=a10; Y[q1*64+co0+1]=a11; Y[q1*64+co0+2]=a12; Y[q1*64+co0+3]=a13;
  }
  __syncthreads();
  // ---- epilogue: sum 8 slabs + bias + dense + residual ----
  {
    int q = t>>6, co = t&63;
    int n = qbase + q;
    float y = cb[co] + db[co];
    #pragma unroll
    for (int g=0; g<8; g++) y += Yw[g*512 + q*64 + co];
    const float* xr = xin + (size_t)n*64;
    for (int ci=0; ci<64; ci++) y += fmaxf(xr[ci], 0.f) * dw[ci*64+co];
    xout[(size_t)n*64+co] = y + xr[co];
  }
}

// ---------------- final cconv layer: wave=q, lane=k, butterfly reduce ----------------
__global__ __launch_bounds__(512) void k_cconvfinal(const float* __restrict__ xin, const int* __restrict__ nbrs,
    const float* __restrict__ gw, const unsigned char* __restrict__ gb,
    const float* __restrict__ W3, const float* __restrict__ cb3,
    const float* __restrict__ dw3, const float* __restrict__ db3,
    const float* __restrict__ pos, const float* __restrict__ pos2, float* __restrict__ outp){
  extern __shared__ float smem[];
  float* Bs = smem;            // 8 x 4096 (NOT swizzled; reads match writes)
  float* Yf = smem + 32768;    // 24 floats
  int t = threadIdx.x;
  int lane = t & 63, w = t >> 6;
  int qbase = blockIdx.x*8;
  #pragma unroll
  for (int i=0;i<16;i++) ((float4*)Bs)[i*512+t] = make_float4(0.f,0.f,0.f,0.f);
  if (t < 24) Yf[t] = 0.f;
  __syncthreads();
  {
    int n = qbase + w;
    const float4* gw4 = (const float4*)(gw + (size_t)n*KN*8);
    const uint2*  gb2 = (const uint2*)(gb + (size_t)n*KN*8);
    const int* nb = nbrs + n*KN;
    float4 g0 = gw4[0], g1 = gw4[1];
    uint2  gv = gb2[0];
    int nbr1 = nb[1];
    float xv = fmaxf(xin[(size_t)nb[0]*64 + lane], 0.f);
    float* Bw = Bs + w*4096 + lane;
    for (int k=0;k<KN;k++){
      float4 cg0=g0, cg1=g1; uint2 cgv=gv; float cxv=xv;
      int nbrn = nbr1;
      if (k<KN-1){
        g0 = gw4[(k+1)*2]; g1 = gw4[(k+1)*2+1]; gv = gb2[k+1];
        xv = fmaxf(xin[(size_t)nbrn*64 + lane], 0.f);
        if (k<KN-2) nbr1 = nb[k+2];
      }
      float wsum = cg0.x+cg0.y+cg0.z+cg0.w+cg1.x+cg1.y+cg1.z+cg1.w;
      if (wsum > 0.f){
        unsigned bx = cgv.x, by = cgv.y;
        atomicAdd(Bw + (int)( bx      &255u)*64, cg0.x*cxv);
        atomicAdd(Bw + (int)((bx>> 8) &255u)*64, cg0.y*cxv);
        atomicAdd(Bw + (int)((bx>>16) &255u)*64, cg0.z*cxv);
        atomicAdd(Bw + (int)( bx>>24       )*64, cg0.w*cxv);
        atomicAdd(Bw + (int)( by      &255u)*64, cg1.x*cxv);
        atomicAdd(Bw + (int)((by>> 8) &255u)*64, cg1.y*cxv);
        atomicAdd(Bw + (int)((by>>16) &255u)*64, cg1.z*cxv);
        atomicAdd(Bw + (int)( by>>24       )*64, cg1.w*cxv);
      }
    }
  }
  __syncthreads();
  {
    float a0=0.f, a1=0.f, a2=0.f;
    #pragma unroll 4
    for (int i=0;i<16;i++){
      int k = i*256 + lane*4;
      float4 b = *(const float4*)&Bs[w*4096 + k];
      const float* wp = W3 + (size_t)k*3;
      float4 wa = *(const float4*)wp;
      float4 wb = *(const float4*)(wp+4);
      float4 wc = *(const float4*)(wp+8);
      a0 += b.x*wa.x + b.y*wa.w + b.z*wb.z + b.w*wc.y;
      a1 += b.x*wa.y + b.y*wb.x + b.z*wb.w + b.w*wc.z;
      a2 += b.x*wa.z + b.y*wb.y + b.z*wc.x + b.w*wc.w;
    }
    #pragma unroll
    for (int m=1; m<64; m<<=1){
      a0 += __shfl_xor(a0, m);
      a1 += __shfl_xor(a1, m);
      a2 += __shfl_xor(a2, m);
    }
    if (lane == 0){
      Yf[w*3+0] = a0; Yf[w*3+1] = a1; Yf[w*3+2] = a2;
    }
  }
  __syncthreads();
  if (t < 24){
    int q = t/3, co = t%3;
    int n = qbase + q;
    float y = Yf[t] + cb3[co] + db3[co];
    for (int cc=0; cc<64; cc++) y += fmaxf(xin[(size_t)n*64+cc],0.f)*dw3[cc*3+co];
    float pc = y*(1.f/128.f);
    float po = pos2[n*3+co] + pc;
    outp[n*3+co] = po;
    outp[NP*3 + n*3+co] = (po - pos[n*3+co]) / 0.02f;
  }
}

extern "C" void kernel_launch(void* const* d_in, const int* in_sizes, int n_in,
                              void* d_out, int out_size, void* d_ws, size_t ws_size,
                              hipStream_t stream) {
  const float* pos   = (const float*)d_in[0];
  const float* vel   = (const float*)d_in[1];
  const int*   fn    = (const int*)d_in[4];
  const float* cw0f  = (const float*)d_in[6];
  const float* cb0f  = (const float*)d_in[7];
  const float* cw1   = (const float*)d_in[10];
  const float* cb1   = (const float*)d_in[11];
  const float* cw2   = (const float*)d_in[12];
  const float* cb2   = (const float*)d_in[13];
  const float* cw3   = (const float*)d_in[14];
  const float* cb3   = (const float*)d_in[15];
  const float* dw1   = (const float*)d_in[16];
  const float* db1   = (const float*)d_in[17];
  const float* dw2   = (const float*)d_in[18];
  const float* db2   = (const float*)d_in[19];
  const float* dw3   = (const float*)d_in[20];
  const float* db3   = (const float*)d_in[21];
  const float* selfW = (const float*)d_in[22];
  const float* selfb = (const float*)d_in[23];
  const float* srcW  = (const float*)d_in[24];
  const float* srcb  = (const float*)d_in[25];
  const float* lna   = (const float*)d_in[26];
  const float* lnb   = (const float*)d_in[27];
  const float* ffw1  = (const float*)d_in[28];
  const float* ffb1  = (const float*)d_in[29];
  const float* ffw2  = (const float*)d_in[30];
  const float* ffb2  = (const float*)d_in[31];

  float* ws = (float*)d_ws;
  float* pos2   = ws + 0;          // 24576
  float* feats4 = ws + 24576;      // 32768
  float* a0f    = ws + 57344;      // 262144
  float* Q1     = ws + 319488;     // 262144
  float* K1     = ws + 581632;     // 262144
  float* V1     = ws + 843776;     // 262144
  float* Q2     = ws + 1105920;    // 262144
  float* h1     = ws + 1368064;    // 262144
  float* K2     = ws + 1630208;    // 262144
  float* V2     = ws + 1892352;    // 262144
  float* h2     = ws + 2154496;    // 262144
  float* Pacc   = ws + 2416640;    // 4194304
  float* Pml    = ws + 6610944;    // 262144
  float* x0     = ws + 6873088;    // 524288
  float* x1     = ws + 7397376;    // 524288
  float* x2     = ws + 7921664;    // 524288 -> ends 8445952
  float* gw     = ws + 8445952;    // 2097152 -> ends 10543104
  unsigned char* gb = (unsigned char*)(ws + 10543104);  // 2 MB

  float* outp = (float*)d_out;

  hipFuncSetAttribute(reinterpret_cast<const void*>(k_cconvbig),
                      hipFuncAttributeMaxDynamicSharedMemorySize, 147456);
  hipFuncSetAttribute(reinterpret_cast<const void*>(k_cconvfinal),
                      hipFuncAttributeMaxDynamicSharedMemorySize, 131200);

  k_prep<<<NP/256, 256, 0, stream>>>(pos, vel, pos2, feats4);
  k_geom<<<NP*KN/256, 256, 0, stream>>>(pos2, fn, gw, gb);
  k_cconv0<<<NP/16, 256, 0, stream>>>(feats4, fn, gw, gb, cw0f, cb0f, a0f);
  k_lnproj1<<<NP/4, 128, 0, stream>>>(a0f, lna, lnb, selfW, selfb, srcW, srcb, Q1, K1, V1, Q2);
  k_attn_part<<<dim3(NP/64, 16), 64, 0, stream>>>(Q1, K1, V1, Pacc, Pml);
  k_merge<<<NP/4, 128, 0, stream>>>(Pacc, Pml, a0f, selfW+3072, selfb+96, h1);
  k_projkv<<<NP/4, 128, 0, stream>>>(h1, srcW, srcb, K2, V2);
  k_attn_part<<<dim3(NP/64, 16), 64, 0, stream>>>(Q2, K2, V2, Pacc, Pml);
  k_merge<<<NP/4, 128, 0, stream>>>(Pacc, Pml, a0f, srcW+3072, srcb+96, h2);
  k_lnffn<<<NP/4, 128, 0, stream>>>(h2, lna, lnb, ffw1, ffb1, ffw2, ffb2, x0);
  k_cconvbig<<<NP/8, 512, 147456, stream>>>(x0, fn, gw, gb, cw1, cb1, dw1, db1, x1);
  k_cconvbig<<<NP/8, 512, 147456, stream>>>(x1, fn, gw, gb, cw2, cb2, dw2, db2, x2);
  k_cconvfinal<<<NP/8, 512, 131200, stream>>>(x2, fn, gw, gb, cw3, cb3, dw3, db3, pos, pos2, outp);
}